// Round 1
// baseline (432.354 us; speedup 1.0000x reference)
//
#include <hip/hip_runtime.h>
#include <stdint.h>
#include <math.h>

#ifndef M_PI
#define M_PI 3.14159265358979323846
#endif

#define NNODES 2048
#define L2DIM  16
#define CIN    384
#define CHID   256

typedef __attribute__((ext_vector_type(8))) short short8;
typedef __attribute__((ext_vector_type(4))) float f32x4;
typedef unsigned short u16;
typedef unsigned int   u32;

#define LOF(i) ((i) < 1 ? 0 : ((i) < 4 ? 1 : ((i) < 9 ? 2 : 3)))

static __device__ __forceinline__ u16 f2bf(float f) {
  u32 u = __builtin_bit_cast(u32, f);
  u = u + 0x7FFFu + ((u >> 16) & 1u);   // RNE
  return (u16)(u >> 16);
}
static __device__ __forceinline__ float bf2f(u16 b) {
  u32 u = ((u32)b) << 16;
  return __builtin_bit_cast(float, u);
}

// ---------------------------------------------------------------------------
// Gaunt coefficient table: G[i][j][k] (16^3) with per-path normalization
// sqrt(2*l3+1)/sqrt(fanin[l3]) folded in. Same GL(16) x uniform(32) quadrature
// as the reference (exact for these band-limited integrands).
// ---------------------------------------------------------------------------
__global__ void gaunt_init_kernel(float* __restrict__ Gout) {
  __shared__ double s_xg[16], s_wg[16];
  __shared__ float  s_Y[16][512];
  __shared__ float  s_W[512];
  int tid = threadIdx.x;
  if (tid < 16) {
    const int n = 16;
    double x = cos(M_PI * (tid + 0.75) / (n + 0.5));
    double p1 = 0.0, dp = 1.0;
    for (int it = 0; it < 100; ++it) {
      double p0 = 1.0; p1 = x;
      for (int kk = 2; kk <= n; ++kk) { double p2 = ((2.0*kk-1.0)*x*p1 - (kk-1.0)*p0)/kk; p0 = p1; p1 = p2; }
      dp = n * (x*p1 - p0) / (x*x - 1.0);
      double dx = p1 / dp;
      x -= dx;
      if (fabs(dx) < 3e-16) break;
    }
    { double p0 = 1.0; p1 = x;
      for (int kk = 2; kk <= n; ++kk) { double p2 = ((2.0*kk-1.0)*x*p1 - (kk-1.0)*p0)/kk; p0 = p1; p1 = p2; }
      dp = n * (x*p1 - p0) / (x*x - 1.0); }
    s_xg[tid] = x;
    s_wg[tid] = 2.0 / ((1.0 - x*x) * dp * dp);
  }
  __syncthreads();
  for (int p = tid; p < 512; p += blockDim.x) {
    int it = p >> 5, ip = p & 31;
    double ct = s_xg[it];
    double st = sqrt(fmax(0.0, 1.0 - ct*ct));
    double phi = 2.0 * M_PI * (double)ip / 32.0;
    double P[4][4];
    P[0][0] = sqrt(1.0 / (4.0 * M_PI));
    for (int m = 1; m <= 3; ++m)
      P[m][m] = sqrt((2.0*m + 1.0) / (2.0*m)) * st * P[m-1][m-1];
    for (int m = 0; m <= 3; ++m) {
      if (m + 1 <= 3) P[m+1][m] = sqrt(2.0*m + 3.0) * ct * P[m][m];
      for (int l = m + 2; l <= 3; ++l) {
        double a = sqrt((4.0*(double)l*l - 1.0) / ((double)l*l - (double)m*m));
        double b = sqrt(((double)(l-1)*(l-1) - (double)m*m) / (4.0*(double)(l-1)*(l-1) - 1.0));
        P[l][m] = a * (ct * P[l-1][m] - b * P[l-2][m]);
      }
    }
    for (int l = 0; l <= 3; ++l)
      for (int m = -l; m <= l; ++m) {
        int idx = l*l + l + m;
        double y;
        if (m == 0)     y = P[l][0];
        else if (m > 0) y = sqrt(2.0) * P[l][m]  * cos((double)m * phi);
        else            y = sqrt(2.0) * P[l][-m] * sin((double)(-m) * phi);
        s_Y[idx][p] = (float)y;
      }
    s_W[p] = (float)(s_wg[it] * (2.0 * M_PI / 32.0));
  }
  __syncthreads();
  int e = blockIdx.x * 256 + tid;   // grid = 16 blocks -> 4096 entries
  if (e < 4096) {
    int i = e >> 8, j = (e >> 4) & 15, k = e & 15;
    double g = 0.0;
    for (int p = 0; p < 512; ++p)
      g += (double)s_Y[i][p] * (double)s_Y[j][p] * ((double)s_Y[k][p] * (double)s_W[p]);
    if (fabs(g) < 1e-6) g = 0.0;   // ref zeroes |G|<1e-10 (true zeros here are <1e-8 noise)
    int l3 = LOF(k);
    const double fan[4] = {4.0, 6.0, 7.0, 6.0};
    g *= sqrt((2.0*(double)l3 + 1.0) / fan[l3]);
    Gout[e] = (float)g;
  }
}

// ---------------------------------------------------------------------------
// Transpose + f32->bf16 convert: src [nmat][R][C] f32 -> dst [nmat][C][R] bf16
// ---------------------------------------------------------------------------
__global__ __launch_bounds__(256) void transpose_bf16_kernel(
    const float* __restrict__ src, u16* __restrict__ dst, int R, int C) {
  __shared__ float tile[32][33];
  int mat = blockIdx.z;
  int r0 = blockIdx.y * 32, c0 = blockIdx.x * 32;
  const float* s = src + (size_t)mat * R * C;
  u16* d = dst + (size_t)mat * R * C;
  int tx = threadIdx.x & 31, ty = threadIdx.x >> 5;
  for (int rr = ty; rr < 32; rr += 8)
    tile[rr][tx] = s[(size_t)(r0 + rr) * C + (c0 + tx)];
  __syncthreads();
  for (int cc = ty; cc < 32; cc += 8)
    d[(size_t)(c0 + cc) * R + (r0 + tx)] = f2bf(tile[tx][cc]);
}

// ---------------------------------------------------------------------------
// Equivariant layernorm: center l=0 over C, RMS over (16,384), per-degree
// affine, norm_b on l=0 only. Writes bf16 [n][16][384].
// ---------------------------------------------------------------------------
__global__ __launch_bounds__(256) void norm_kernel(
    const float* __restrict__ x, const float* __restrict__ nw,
    const float* __restrict__ nb, u16* __restrict__ xnb) {
  int n = blockIdx.x, tid = threadIdx.x;
  const float* xr = x + (size_t)n * (L2DIM * CIN);
  __shared__ float xs[L2DIM * CIN];
  __shared__ float2 red[4];
  float4 v[6];
  float ssq = 0.f;
#pragma unroll
  for (int q = 0; q < 6; ++q) {
    v[q] = reinterpret_cast<const float4*>(xr)[tid * 6 + q];
    ssq += v[q].x*v[q].x + v[q].y*v[q].y + v[q].z*v[q].z + v[q].w*v[q].w;
    reinterpret_cast<float4*>(xs)[tid * 6 + q] = v[q];
  }
  __syncthreads();
  float m0p = 0.f;
  for (int c = tid; c < CIN; c += 256) m0p += xs[c];
  // block reduce (m0p, ssq)
  float a = m0p, b = ssq;
#pragma unroll
  for (int off = 32; off > 0; off >>= 1) { a += __shfl_down(a, off, 64); b += __shfl_down(b, off, 64); }
  int lane = tid & 63, wid = tid >> 6;
  if (lane == 0) red[wid] = make_float2(a, b);
  __syncthreads();
  float sum0 = red[0].x + red[1].x + red[2].x + red[3].x;
  float ssqt = red[0].y + red[1].y + red[2].y + red[3].y;
  float mean0 = sum0 * (1.0f / CIN);
  float ss = ssqt - (float)CIN * mean0 * mean0;   // sum of squares after centering l=0
  float rstd = rsqrtf(ss * (1.0f / (L2DIM * CIN)) + 1e-5f);

  int lm = tid >> 4;          // 24 consecutive elems per thread, all in one row
  int l = LOF(lm);
  bool row0 = (lm == 0);
  int cbase = (tid & 15) * 24;
  u16* orow = xnb + (size_t)n * (L2DIM * CIN) + (size_t)tid * 24;
#pragma unroll
  for (int q = 0; q < 6; ++q) {
    int c = cbase + q * 4;
    float4 w4 = *reinterpret_cast<const float4*>(&nw[l * CIN + c]);
    float4 b4 = row0 ? *reinterpret_cast<const float4*>(&nb[c]) : make_float4(0,0,0,0);
    float sub = row0 ? mean0 : 0.f;
    float o0 = (v[q].x - sub) * rstd * w4.x + b4.x;
    float o1 = (v[q].y - sub) * rstd * w4.y + b4.y;
    float o2 = (v[q].z - sub) * rstd * w4.z + b4.z;
    float o3 = (v[q].w - sub) * rstd * w4.w + b4.w;
    ushort4 pk;
    pk.x = f2bf(o0); pk.y = f2bf(o1); pk.z = f2bf(o2); pk.w = f2bf(o3);
    *reinterpret_cast<ushort4*>(&orow[q * 4]) = pk;
  }
}

// ---------------------------------------------------------------------------
// Per-degree GEMM with MFMA 16x16x32 bf16.
// A: [2048][16][KD] bf16 rows gathered per l.  BT: [4][ND][KD] bf16.
// BM=64, BN=128, BK=64, 4 waves (2x2), wave tile 32x64.
// global_load_lds staging with XOR-swizzled source (read undoes the XOR).
// ---------------------------------------------------------------------------
template <int KD, int ND, bool SECOND>
__global__ __launch_bounds__(256) void so3_gemm_kernel(
    const u16* __restrict__ A, const u16* __restrict__ BT,
    const float* __restrict__ bias, const float* __restrict__ resid,
    u16* __restrict__ outb, float* __restrict__ outf) {
  int l = blockIdx.z;
  int twol1 = 2 * l + 1;
  int mtiles = (NNODES * twol1) >> 6;
  if ((int)blockIdx.x >= mtiles) return;
  int col0 = blockIdx.y * 128;
  int tid = threadIdx.x, lane = tid & 63, wid = tid >> 6;
  int wm = wid >> 1, wn = wid & 1;

  __shared__ u16 Asm[64 * 64];    //  8 KB
  __shared__ u16 Bsm[128 * 64];   // 16 KB

  // staging source addresses (swizzled slot: lds[r][s] holds global slot s^(r&7))
  const u16* asrc[2];
#pragma unroll
  for (int rr = 0; rr < 2; ++rr) {
    int r = wid * 16 + rr * 8 + (lane >> 3);
    int Rg = blockIdx.x * 64 + r;
    int node = Rg / twol1;
    int lm = l * l + (Rg - node * twol1);
    asrc[rr] = A + (size_t)(node * L2DIM + lm) * KD + ((lane & 7) ^ (r & 7)) * 8;
  }
  const u16* bsrc[4];
#pragma unroll
  for (int rr = 0; rr < 4; ++rr) {
    int r = wid * 32 + rr * 8 + (lane >> 3);
    int colg = col0 + r;
    bsrc[rr] = BT + (size_t)(l * ND + colg) * KD + ((lane & 7) ^ (r & 7)) * 8;
  }

  f32x4 acc[2][4];
#pragma unroll
  for (int i = 0; i < 2; ++i)
#pragma unroll
    for (int j = 0; j < 4; ++j) acc[i][j] = (f32x4){0.f, 0.f, 0.f, 0.f};

  for (int kt = 0; kt < KD / 64; ++kt) {
#pragma unroll
    for (int rr = 0; rr < 2; ++rr)
      __builtin_amdgcn_global_load_lds(
          (const __attribute__((address_space(1))) void*)(asrc[rr] + kt * 64),
          (__attribute__((address_space(3))) void*)(&Asm[wid * 1024 + rr * 512]),
          16, 0, 0);
#pragma unroll
    for (int rr = 0; rr < 4; ++rr)
      __builtin_amdgcn_global_load_lds(
          (const __attribute__((address_space(1))) void*)(bsrc[rr] + kt * 64),
          (__attribute__((address_space(3))) void*)(&Bsm[wid * 2048 + rr * 512]),
          16, 0, 0);
    __syncthreads();
#pragma unroll
    for (int ks = 0; ks < 2; ++ks) {
      short8 af[2], bfv[4];
#pragma unroll
      for (int mf = 0; mf < 2; ++mf) {
        int row = wm * 32 + mf * 16 + (lane & 15);
        int slot = (ks * 4 + (lane >> 4)) ^ (row & 7);
        af[mf] = *reinterpret_cast<const short8*>(&Asm[row * 64 + slot * 8]);
      }
#pragma unroll
      for (int nf = 0; nf < 4; ++nf) {
        int brow = wn * 64 + nf * 16 + (lane & 15);
        int slot = (ks * 4 + (lane >> 4)) ^ (brow & 7);
        bfv[nf] = *reinterpret_cast<const short8*>(&Bsm[brow * 64 + slot * 8]);
      }
#pragma unroll
      for (int mf = 0; mf < 2; ++mf)
#pragma unroll
        for (int nf = 0; nf < 4; ++nf)
          acc[mf][nf] = __builtin_amdgcn_mfma_f32_16x16x32_bf16(af[mf], bfv[nf], acc[mf][nf], 0, 0, 0);
    }
    __syncthreads();
  }

  // epilogue: D row = (lane>>4)*4 + j, col = lane&15 (m89-verified C/D layout)
#pragma unroll
  for (int mf = 0; mf < 2; ++mf) {
#pragma unroll
    for (int jj = 0; jj < 4; ++jj) {
      int Rg = blockIdx.x * 64 + wm * 32 + mf * 16 + (lane >> 4) * 4 + jj;
      int node = Rg / twol1;
      int lm = l * l + (Rg - node * twol1);
      size_t rowoff = (size_t)(node * L2DIM + lm);
#pragma unroll
      for (int nf = 0; nf < 4; ++nf) {
        int colg = col0 + wn * 64 + nf * 16 + (lane & 15);
        float vv = acc[mf][nf][jj];
        if (l == 0) vv += bias[colg];
        if (!SECOND) {
          outb[rowoff * ND + colg] = f2bf(vv);
        } else {
          outf[rowoff * ND + colg] = vv + resid[rowoff * ND + colg];
        }
      }
    }
  }
}

// ---------------------------------------------------------------------------
// Depthwise Gaunt tensor product. Thread = (node, channel). h/t in registers;
// compile-time unrolled (l,m) superset via selection rules; runtime coeffs
// from the precomputed table (zeros cost one dead fma).
// ---------------------------------------------------------------------------
__global__ __launch_bounds__(256) void gaunt_kernel(
    const u16* __restrict__ hb, const float* __restrict__ wg,
    const float* __restrict__ Gt, u16* __restrict__ tb) {
  int n = blockIdx.x, c = threadIdx.x;
  const u16* hr = hb + (size_t)n * (L2DIM * CHID) + c;
  float h[16];
#pragma unroll
  for (int i = 0; i < 16; ++i) h[i] = bf2f(hr[i * CHID]);

  float wgv[23];
  {
    int p = 0;
#pragma unroll
    for (int l1 = 0; l1 < 4; ++l1)
#pragma unroll
      for (int l2 = 0; l2 < 4; ++l2)
#pragma unroll
        for (int l3 = 0; l3 < 4; ++l3) {
          int lo = l1 - l2; if (lo < 0) lo = -lo;
          if (!(l3 >= lo && l3 <= l1 + l2 && (((l1 + l2 + l3) & 1) == 0))) continue;
          wgv[p++] = wg[(size_t)((l1 * 4 + l2) * 4 + l3) * CHID + c];
        }
  }

  float t[16];
#pragma unroll
  for (int k = 0; k < 16; ++k) t[k] = 0.f;

  {
    int p = 0;
#pragma unroll
    for (int l1 = 0; l1 < 4; ++l1)
#pragma unroll
      for (int l2 = 0; l2 < 4; ++l2)
#pragma unroll
        for (int l3 = 0; l3 < 4; ++l3) {
          int lo = l1 - l2; if (lo < 0) lo = -lo;
          if (!(l3 >= lo && l3 <= l1 + l2 && (((l1 + l2 + l3) & 1) == 0))) continue;
          float w = wgv[p++];
#pragma unroll
          for (int m1 = -l1; m1 <= l1; ++m1)
#pragma unroll
            for (int m2 = -l2; m2 <= l2; ++m2)
#pragma unroll
              for (int m3 = -l3; m3 <= l3; ++m3) {
                int aa = m1 < 0 ? -m1 : m1, bb = m2 < 0 ? -m2 : m2, cc = m3 < 0 ? -m3 : m3;
                int neg = (m1 < 0) + (m2 < 0) + (m3 < 0);
                if (neg & 1) continue;                                   // odd sin count -> 0
                if (!(aa + bb == cc || bb + cc == aa || cc + aa == bb)) continue; // phi rule
                int i = l1 * l1 + l1 + m1;
                int j = l2 * l2 + l2 + m2;
                int k = l3 * l3 + l3 + m3;
                float g = Gt[(i * 16 + j) * 16 + k];
                t[k] = fmaf(g * w, h[i] * h[j], t[k]);
              }
        }
  }

  u16* tr = tb + (size_t)n * (L2DIM * CHID) + c;
#pragma unroll
  for (int k = 0; k < 16; ++k) tr[k * CHID] = f2bf(t[k]);
}

// ---------------------------------------------------------------------------
extern "C" void kernel_launch(void* const* d_in, const int* in_sizes, int n_in,
                              void* d_out, int out_size, void* d_ws, size_t ws_size,
                              hipStream_t stream) {
  const float* inputs = (const float*)d_in[0];
  // d_in[1] = batch (unused: drop paths disabled)
  const float* norm_w = (const float*)d_in[2];
  const float* norm_b = (const float*)d_in[3];
  const float* w1     = (const float*)d_in[4];
  const float* b1     = (const float*)d_in[5];
  const float* wga    = (const float*)d_in[6];
  const float* w2     = (const float*)d_in[7];
  const float* b2     = (const float*)d_in[8];
  float* out = (float*)d_out;

  uint8_t* ws = (uint8_t*)d_ws;
  float* Gt  = (float*)(ws + 0);            //  16 KB
  u16*   w1t = (u16*)(ws + 16384);          // [4][256][384] bf16, 768 KB
  u16*   w2t = (u16*)(ws + 802816);         // [4][384][256] bf16, 768 KB
  u16*   xnb = (u16*)(ws + 1589248);        // [2048][16][384] bf16, 24 MB
  u16*   tb  = xnb;                         // reuse after GEMM1 consumed xnb
  u16*   hb  = (u16*)(ws + 26755072);       // [2048][16][256] bf16, 16 MB
  // total ws usage: 43,532,288 bytes

  gaunt_init_kernel<<<16, 256, 0, stream>>>(Gt);
  transpose_bf16_kernel<<<dim3(8, 12, 4), 256, 0, stream>>>(w1, w1t, 384, 256);
  transpose_bf16_kernel<<<dim3(12, 8, 4), 256, 0, stream>>>(w2, w2t, 256, 384);
  norm_kernel<<<NNODES, 256, 0, stream>>>(inputs, norm_w, norm_b, xnb);
  so3_gemm_kernel<CIN, CHID, false><<<dim3(224, 2, 4), 256, 0, stream>>>(
      xnb, w1t, b1, nullptr, hb, nullptr);
  gaunt_kernel<<<NNODES, 256, 0, stream>>>(hb, wga, Gt, tb);
  so3_gemm_kernel<CHID, CIN, true><<<dim3(224, 3, 4), 256, 0, stream>>>(
      tb, w2t, b2, inputs, nullptr, out);
}

// Round 2
// 198.320 us; speedup vs baseline: 2.1801x; 2.1801x over previous
//
#include <hip/hip_runtime.h>
#include <stdint.h>
#include <math.h>
#include <array>
#include <utility>

#ifndef M_PI
#define M_PI 3.14159265358979323846
#endif

#define NNODES 2048
#define L2DIM  16
#define CIN    384
#define CHID   256

typedef __attribute__((ext_vector_type(8))) short short8;
typedef __attribute__((ext_vector_type(4))) float f32x4;
typedef unsigned short u16;
typedef unsigned int   u32;

#define LOF(i) ((i) < 1 ? 0 : ((i) < 4 ? 1 : ((i) < 9 ? 2 : 3)))

static __device__ __forceinline__ u16 f2bf(float f) {
  u32 u = __builtin_bit_cast(u32, f);
  u = u + 0x7FFFu + ((u >> 16) & 1u);   // RNE
  return (u16)(u >> 16);
}
static __device__ __forceinline__ float bf2f(u16 b) {
  u32 u = ((u32)b) << 16;
  return __builtin_bit_cast(float, u);
}

// ---------------------------------------------------------------------------
// Compile-time term enumeration for the Gaunt depthwise TP.
// Superset selection rules (validated in round 1): path triangle+parity,
// m-parity (even sin count), phi frequency rule (|m| sum condition).
// ---------------------------------------------------------------------------
struct TermT { unsigned char i, j, k, p; };
struct PathT { unsigned char l1, l2, l3; };

__host__ __device__ constexpr bool path_ok(int l1, int l2, int l3) {
  int lo = l1 > l2 ? l1 - l2 : l2 - l1;
  return l3 >= lo && l3 <= l1 + l2 && (((l1 + l2 + l3) & 1) == 0);
}
__host__ __device__ constexpr bool term_ok(int m1, int m2, int m3) {
  int aa = m1 < 0 ? -m1 : m1, bb = m2 < 0 ? -m2 : m2, cc = m3 < 0 ? -m3 : m3;
  int neg = (m1 < 0) + (m2 < 0) + (m3 < 0);
  if (neg & 1) return false;
  return (aa + bb == cc) || (bb + cc == aa) || (cc + aa == bb);
}
constexpr int count_paths() {
  int n = 0;
  for (int l1 = 0; l1 < 4; ++l1) for (int l2 = 0; l2 < 4; ++l2) for (int l3 = 0; l3 < 4; ++l3)
    if (path_ok(l1, l2, l3)) ++n;
  return n;
}
constexpr int count_terms() {
  int n = 0;
  for (int l1 = 0; l1 < 4; ++l1) for (int l2 = 0; l2 < 4; ++l2) for (int l3 = 0; l3 < 4; ++l3) {
    if (!path_ok(l1, l2, l3)) continue;
    for (int m1 = -l1; m1 <= l1; ++m1) for (int m2 = -l2; m2 <= l2; ++m2) for (int m3 = -l3; m3 <= l3; ++m3)
      if (term_ok(m1, m2, m3)) ++n;
  }
  return n;
}
constexpr int NPATHS = count_paths();   // 23
constexpr int NT     = count_terms();   // 359

constexpr std::array<PathT, NPATHS> build_paths() {
  std::array<PathT, NPATHS> a{};
  int n = 0;
  for (int l1 = 0; l1 < 4; ++l1) for (int l2 = 0; l2 < 4; ++l2) for (int l3 = 0; l3 < 4; ++l3)
    if (path_ok(l1, l2, l3)) a[n++] = PathT{(unsigned char)l1, (unsigned char)l2, (unsigned char)l3};
  return a;
}
constexpr std::array<TermT, NT> build_terms() {
  std::array<TermT, NT> a{};
  int n = 0, p = 0;
  for (int l1 = 0; l1 < 4; ++l1) for (int l2 = 0; l2 < 4; ++l2) for (int l3 = 0; l3 < 4; ++l3) {
    if (!path_ok(l1, l2, l3)) continue;
    for (int m1 = -l1; m1 <= l1; ++m1) for (int m2 = -l2; m2 <= l2; ++m2) for (int m3 = -l3; m3 <= l3; ++m3)
      if (term_ok(m1, m2, m3))
        a[n++] = TermT{(unsigned char)(l1 * l1 + l1 + m1),
                       (unsigned char)(l2 * l2 + l2 + m2),
                       (unsigned char)(l3 * l3 + l3 + m3),
                       (unsigned char)p};
    ++p;
  }
  return a;
}
constexpr auto PATHS_ARR = build_paths();
constexpr auto TERMS     = build_terms();

// Fold-expression expansion: every index below is a compile-time constant,
// so t/h/wgv are guaranteed register-resident (no runtime array indexing).
template <size_t... Is>
__device__ __forceinline__ void gaunt_terms(std::index_sequence<Is...>,
    float* __restrict__ t, const float* __restrict__ h,
    const float* __restrict__ wgv, const float* __restrict__ pg) {
  ((t[TERMS[Is].k] = fmaf(pg[Is] * wgv[TERMS[Is].p],
                          h[TERMS[Is].i] * h[TERMS[Is].j],
                          t[TERMS[Is].k])), ...);
}
template <size_t... Ps>
__device__ __forceinline__ void load_wgv(std::index_sequence<Ps...>,
    float* __restrict__ wgv, const float* __restrict__ wg, int c) {
  ((wgv[Ps] = wg[(size_t)(((int)PATHS_ARR[Ps].l1 * 4 + (int)PATHS_ARR[Ps].l2) * 4
                          + (int)PATHS_ARR[Ps].l3) * CHID + c]), ...);
}

// ---------------------------------------------------------------------------
// Gaunt coefficient init: computes the packed per-term coefficient table
// pg[NT] (term order = compile-time TERMS order) via the same GL(16) x
// uniform(32) quadrature as the reference, with sqrt(2*l3+1)/sqrt(fanin)
// folded in.
// ---------------------------------------------------------------------------
__global__ void gaunt_init_kernel(float* __restrict__ pg) {
  __shared__ double s_xg[16], s_wg[16];
  __shared__ float  s_Y[16][512];
  __shared__ float  s_W[512];
  int tid = threadIdx.x;
  if (tid < 16) {
    const int n = 16;
    double x = cos(M_PI * (tid + 0.75) / (n + 0.5));
    double p1 = 0.0, dp = 1.0;
    for (int it = 0; it < 100; ++it) {
      double p0 = 1.0; p1 = x;
      for (int kk = 2; kk <= n; ++kk) { double p2 = ((2.0*kk-1.0)*x*p1 - (kk-1.0)*p0)/kk; p0 = p1; p1 = p2; }
      dp = n * (x*p1 - p0) / (x*x - 1.0);
      double dx = p1 / dp;
      x -= dx;
      if (fabs(dx) < 3e-16) break;
    }
    { double p0 = 1.0; p1 = x;
      for (int kk = 2; kk <= n; ++kk) { double p2 = ((2.0*kk-1.0)*x*p1 - (kk-1.0)*p0)/kk; p0 = p1; p1 = p2; }
      dp = n * (x*p1 - p0) / (x*x - 1.0); }
    s_xg[tid] = x;
    s_wg[tid] = 2.0 / ((1.0 - x*x) * dp * dp);
  }
  __syncthreads();
  for (int p = tid; p < 512; p += blockDim.x) {
    int it = p >> 5, ip = p & 31;
    double ct = s_xg[it];
    double st = sqrt(fmax(0.0, 1.0 - ct*ct));
    double phi = 2.0 * M_PI * (double)ip / 32.0;
    double P[4][4];
    P[0][0] = sqrt(1.0 / (4.0 * M_PI));
    for (int m = 1; m <= 3; ++m)
      P[m][m] = sqrt((2.0*m + 1.0) / (2.0*m)) * st * P[m-1][m-1];
    for (int m = 0; m <= 3; ++m) {
      if (m + 1 <= 3) P[m+1][m] = sqrt(2.0*m + 3.0) * ct * P[m][m];
      for (int l = m + 2; l <= 3; ++l) {
        double a = sqrt((4.0*(double)l*l - 1.0) / ((double)l*l - (double)m*m));
        double b = sqrt(((double)(l-1)*(l-1) - (double)m*m) / (4.0*(double)(l-1)*(l-1) - 1.0));
        P[l][m] = a * (ct * P[l-1][m] - b * P[l-2][m]);
      }
    }
    for (int l = 0; l <= 3; ++l)
      for (int m = -l; m <= l; ++m) {
        int idx = l*l + l + m;
        double y;
        if (m == 0)     y = P[l][0];
        else if (m > 0) y = sqrt(2.0) * P[l][m]  * cos((double)m * phi);
        else            y = sqrt(2.0) * P[l][-m] * sin((double)(-m) * phi);
        s_Y[idx][p] = (float)y;
      }
    s_W[p] = (float)(s_wg[it] * (2.0 * M_PI / 32.0));
  }
  __syncthreads();
  // runtime enumeration of term `want` (avoids runtime-indexing the constexpr table)
  int want = blockIdx.x * 256 + tid;
  int n = 0, ti = 0, tj = 0, tk = 0; bool found = false;
  for (int l1 = 0; l1 < 4; ++l1) for (int l2 = 0; l2 < 4; ++l2) for (int l3 = 0; l3 < 4; ++l3) {
    if (!path_ok(l1, l2, l3)) continue;
    for (int m1 = -l1; m1 <= l1; ++m1) for (int m2 = -l2; m2 <= l2; ++m2) for (int m3 = -l3; m3 <= l3; ++m3) {
      if (!term_ok(m1, m2, m3)) continue;
      if (n == want) { ti = l1*l1+l1+m1; tj = l2*l2+l2+m2; tk = l3*l3+l3+m3; found = true; }
      ++n;
    }
  }
  if (found) {
    double g = 0.0;
    for (int p = 0; p < 512; ++p)
      g += (double)s_Y[ti][p] * (double)s_Y[tj][p] * ((double)s_Y[tk][p] * (double)s_W[p]);
    int l3 = LOF(tk);
    const double fan[4] = {4.0, 6.0, 7.0, 6.0};
    g *= sqrt((2.0*(double)l3 + 1.0) / fan[l3]);
    pg[want] = (float)g;
  }
}

// ---------------------------------------------------------------------------
// Transpose + f32->bf16 convert: src [nmat][R][C] f32 -> dst [nmat][C][R] bf16
// ---------------------------------------------------------------------------
__global__ __launch_bounds__(256) void transpose_bf16_kernel(
    const float* __restrict__ src, u16* __restrict__ dst, int R, int C) {
  __shared__ float tile[32][33];
  int mat = blockIdx.z;
  int r0 = blockIdx.y * 32, c0 = blockIdx.x * 32;
  const float* s = src + (size_t)mat * R * C;
  u16* d = dst + (size_t)mat * R * C;
  int tx = threadIdx.x & 31, ty = threadIdx.x >> 5;
  for (int rr = ty; rr < 32; rr += 8)
    tile[rr][tx] = s[(size_t)(r0 + rr) * C + (c0 + tx)];
  __syncthreads();
  for (int cc = ty; cc < 32; cc += 8)
    d[(size_t)(c0 + cc) * R + (r0 + tx)] = f2bf(tile[tx][cc]);
}

// ---------------------------------------------------------------------------
// Equivariant layernorm: center l=0 over C, RMS over (16,384), per-degree
// affine, norm_b on l=0 only. Writes bf16 [n][16][384].
// ---------------------------------------------------------------------------
__global__ __launch_bounds__(256) void norm_kernel(
    const float* __restrict__ x, const float* __restrict__ nw,
    const float* __restrict__ nb, u16* __restrict__ xnb) {
  int n = blockIdx.x, tid = threadIdx.x;
  const float* xr = x + (size_t)n * (L2DIM * CIN);
  __shared__ float xs[L2DIM * CIN];
  __shared__ float2 red[4];
  float4 v[6];
  float ssq = 0.f;
#pragma unroll
  for (int q = 0; q < 6; ++q) {
    v[q] = reinterpret_cast<const float4*>(xr)[tid * 6 + q];
    ssq += v[q].x*v[q].x + v[q].y*v[q].y + v[q].z*v[q].z + v[q].w*v[q].w;
    reinterpret_cast<float4*>(xs)[tid * 6 + q] = v[q];
  }
  __syncthreads();
  float m0p = 0.f;
  for (int c = tid; c < CIN; c += 256) m0p += xs[c];
  float a = m0p, b = ssq;
#pragma unroll
  for (int off = 32; off > 0; off >>= 1) { a += __shfl_down(a, off, 64); b += __shfl_down(b, off, 64); }
  int lane = tid & 63, wid = tid >> 6;
  if (lane == 0) red[wid] = make_float2(a, b);
  __syncthreads();
  float sum0 = red[0].x + red[1].x + red[2].x + red[3].x;
  float ssqt = red[0].y + red[1].y + red[2].y + red[3].y;
  float mean0 = sum0 * (1.0f / CIN);
  float ss = ssqt - (float)CIN * mean0 * mean0;
  float rstd = rsqrtf(ss * (1.0f / (L2DIM * CIN)) + 1e-5f);

  int lm = tid >> 4;
  int l = LOF(lm);
  bool row0 = (lm == 0);
  int cbase = (tid & 15) * 24;
  u16* orow = xnb + (size_t)n * (L2DIM * CIN) + (size_t)tid * 24;
#pragma unroll
  for (int q = 0; q < 6; ++q) {
    int c = cbase + q * 4;
    float4 w4 = *reinterpret_cast<const float4*>(&nw[l * CIN + c]);
    float4 b4 = row0 ? *reinterpret_cast<const float4*>(&nb[c]) : make_float4(0,0,0,0);
    float sub = row0 ? mean0 : 0.f;
    float o0 = (v[q].x - sub) * rstd * w4.x + b4.x;
    float o1 = (v[q].y - sub) * rstd * w4.y + b4.y;
    float o2 = (v[q].z - sub) * rstd * w4.z + b4.z;
    float o3 = (v[q].w - sub) * rstd * w4.w + b4.w;
    ushort4 pk;
    pk.x = f2bf(o0); pk.y = f2bf(o1); pk.z = f2bf(o2); pk.w = f2bf(o3);
    *reinterpret_cast<ushort4*>(&orow[q * 4]) = pk;
  }
}

// ---------------------------------------------------------------------------
// Per-degree GEMM with MFMA 16x16x32 bf16 (unchanged from round 1).
// ---------------------------------------------------------------------------
template <int KD, int ND, bool SECOND>
__global__ __launch_bounds__(256) void so3_gemm_kernel(
    const u16* __restrict__ A, const u16* __restrict__ BT,
    const float* __restrict__ bias, const float* __restrict__ resid,
    u16* __restrict__ outb, float* __restrict__ outf) {
  int l = blockIdx.z;
  int twol1 = 2 * l + 1;
  int mtiles = (NNODES * twol1) >> 6;
  if ((int)blockIdx.x >= mtiles) return;
  int col0 = blockIdx.y * 128;
  int tid = threadIdx.x, lane = tid & 63, wid = tid >> 6;
  int wm = wid >> 1, wn = wid & 1;

  __shared__ u16 Asm[64 * 64];
  __shared__ u16 Bsm[128 * 64];

  const u16* asrc[2];
#pragma unroll
  for (int rr = 0; rr < 2; ++rr) {
    int r = wid * 16 + rr * 8 + (lane >> 3);
    int Rg = blockIdx.x * 64 + r;
    int node = Rg / twol1;
    int lm = l * l + (Rg - node * twol1);
    asrc[rr] = A + (size_t)(node * L2DIM + lm) * KD + ((lane & 7) ^ (r & 7)) * 8;
  }
  const u16* bsrc[4];
#pragma unroll
  for (int rr = 0; rr < 4; ++rr) {
    int r = wid * 32 + rr * 8 + (lane >> 3);
    int colg = col0 + r;
    bsrc[rr] = BT + (size_t)(l * ND + colg) * KD + ((lane & 7) ^ (r & 7)) * 8;
  }

  f32x4 acc[2][4];
#pragma unroll
  for (int i = 0; i < 2; ++i)
#pragma unroll
    for (int j = 0; j < 4; ++j) acc[i][j] = (f32x4){0.f, 0.f, 0.f, 0.f};

  for (int kt = 0; kt < KD / 64; ++kt) {
#pragma unroll
    for (int rr = 0; rr < 2; ++rr)
      __builtin_amdgcn_global_load_lds(
          (const __attribute__((address_space(1))) void*)(asrc[rr] + kt * 64),
          (__attribute__((address_space(3))) void*)(&Asm[wid * 1024 + rr * 512]),
          16, 0, 0);
#pragma unroll
    for (int rr = 0; rr < 4; ++rr)
      __builtin_amdgcn_global_load_lds(
          (const __attribute__((address_space(1))) void*)(bsrc[rr] + kt * 64),
          (__attribute__((address_space(3))) void*)(&Bsm[wid * 2048 + rr * 512]),
          16, 0, 0);
    __syncthreads();
#pragma unroll
    for (int ks = 0; ks < 2; ++ks) {
      short8 af[2], bfv[4];
#pragma unroll
      for (int mf = 0; mf < 2; ++mf) {
        int row = wm * 32 + mf * 16 + (lane & 15);
        int slot = (ks * 4 + (lane >> 4)) ^ (row & 7);
        af[mf] = *reinterpret_cast<const short8*>(&Asm[row * 64 + slot * 8]);
      }
#pragma unroll
      for (int nf = 0; nf < 4; ++nf) {
        int brow = wn * 64 + nf * 16 + (lane & 15);
        int slot = (ks * 4 + (lane >> 4)) ^ (brow & 7);
        bfv[nf] = *reinterpret_cast<const short8*>(&Bsm[brow * 64 + slot * 8]);
      }
#pragma unroll
      for (int mf = 0; mf < 2; ++mf)
#pragma unroll
        for (int nf = 0; nf < 4; ++nf)
          acc[mf][nf] = __builtin_amdgcn_mfma_f32_16x16x32_bf16(af[mf], bfv[nf], acc[mf][nf], 0, 0, 0);
    }
    __syncthreads();
  }

#pragma unroll
  for (int mf = 0; mf < 2; ++mf) {
#pragma unroll
    for (int jj = 0; jj < 4; ++jj) {
      int Rg = blockIdx.x * 64 + wm * 32 + mf * 16 + (lane >> 4) * 4 + jj;
      int node = Rg / twol1;
      int lm = l * l + (Rg - node * twol1);
      size_t rowoff = (size_t)(node * L2DIM + lm);
#pragma unroll
      for (int nf = 0; nf < 4; ++nf) {
        int colg = col0 + wn * 64 + nf * 16 + (lane & 15);
        float vv = acc[mf][nf][jj];
        if (l == 0) vv += bias[colg];
        if (!SECOND) {
          outb[rowoff * ND + colg] = f2bf(vv);
        } else {
          outf[rowoff * ND + colg] = vv + resid[rowoff * ND + colg];
        }
      }
    }
  }
}

// ---------------------------------------------------------------------------
// Depthwise Gaunt tensor product, fully static expansion.
// Thread = (node, channel). h/t/wgv guaranteed register-resident.
// ---------------------------------------------------------------------------
__global__ __launch_bounds__(256, 2) void gaunt_kernel(
    const u16* __restrict__ hb, const float* __restrict__ wg,
    const float* __restrict__ pg, u16* __restrict__ tb) {
  int n = blockIdx.x, c = threadIdx.x;
  const u16* hr = hb + (size_t)n * (L2DIM * CHID) + c;
  float h[16];
#pragma unroll
  for (int i = 0; i < 16; ++i) h[i] = bf2f(hr[i * CHID]);

  float wgv[NPATHS];
  load_wgv(std::make_index_sequence<NPATHS>{}, wgv, wg, c);

  float t[16];
#pragma unroll
  for (int k = 0; k < 16; ++k) t[k] = 0.f;

  gaunt_terms(std::make_index_sequence<NT>{}, t, h, wgv, pg);

  u16* tr = tb + (size_t)n * (L2DIM * CHID) + c;
#pragma unroll
  for (int k = 0; k < 16; ++k) tr[k * CHID] = f2bf(t[k]);
}

// ---------------------------------------------------------------------------
extern "C" void kernel_launch(void* const* d_in, const int* in_sizes, int n_in,
                              void* d_out, int out_size, void* d_ws, size_t ws_size,
                              hipStream_t stream) {
  const float* inputs = (const float*)d_in[0];
  // d_in[1] = batch (unused: drop paths disabled)
  const float* norm_w = (const float*)d_in[2];
  const float* norm_b = (const float*)d_in[3];
  const float* w1     = (const float*)d_in[4];
  const float* b1     = (const float*)d_in[5];
  const float* wga    = (const float*)d_in[6];
  const float* w2     = (const float*)d_in[7];
  const float* b2     = (const float*)d_in[8];
  float* out = (float*)d_out;

  uint8_t* ws = (uint8_t*)d_ws;
  float* pg  = (float*)(ws + 0);            // NT*4 B (< 16 KB slot)
  u16*   w1t = (u16*)(ws + 16384);          // [4][256][384] bf16, 768 KB
  u16*   w2t = (u16*)(ws + 802816);         // [4][384][256] bf16, 768 KB
  u16*   xnb = (u16*)(ws + 1589248);        // [2048][16][384] bf16, 24 MB
  u16*   tb  = xnb;                         // reuse after GEMM1 consumed xnb
  u16*   hb  = (u16*)(ws + 26755072);       // [2048][16][256] bf16, 16 MB

  gaunt_init_kernel<<<2, 256, 0, stream>>>(pg);
  transpose_bf16_kernel<<<dim3(8, 12, 4), 256, 0, stream>>>(w1, w1t, 384, 256);
  transpose_bf16_kernel<<<dim3(12, 8, 4), 256, 0, stream>>>(w2, w2t, 256, 384);
  norm_kernel<<<NNODES, 256, 0, stream>>>(inputs, norm_w, norm_b, xnb);
  so3_gemm_kernel<CIN, CHID, false><<<dim3(224, 2, 4), 256, 0, stream>>>(
      xnb, w1t, b1, nullptr, hb, nullptr);
  gaunt_kernel<<<NNODES, 256, 0, stream>>>(hb, wga, pg, tb);
  so3_gemm_kernel<CHID, CIN, true><<<dim3(224, 3, 4), 256, 0, stream>>>(
      tb, w2t, b2, inputs, nullptr, out);
}

// Round 3
// 93.127 us; speedup vs baseline: 4.6426x; 2.1296x over previous
//
#include <hip/hip_runtime.h>
#include <stdint.h>
#include <math.h>
#include <array>
#include <utility>

#ifndef M_PI
#define M_PI 3.14159265358979323846
#endif

#define NNODES 2048
#define L2DIM  16
#define CIN    384
#define CHID   256

typedef __attribute__((ext_vector_type(8))) short short8;
typedef __attribute__((ext_vector_type(4))) float f32x4;
typedef unsigned short u16;
typedef unsigned int   u32;

#define LOF(i) ((i) < 1 ? 0 : ((i) < 4 ? 1 : ((i) < 9 ? 2 : 3)))

static __device__ __forceinline__ u16 f2bf(float f) {
  u32 u = __builtin_bit_cast(u32, f);
  u = u + 0x7FFFu + ((u >> 16) & 1u);   // RNE
  return (u16)(u >> 16);
}
static __device__ __forceinline__ float bf2f(u16 b) {
  u32 u = ((u32)b) << 16;
  return __builtin_bit_cast(float, u);
}

// ===========================================================================
// COMPILE-TIME Gaunt coefficients.
// The reference's GL(16) x uniform(32) quadrature is EXACT for these
// band-limited integrands, so we evaluate the same integrals analytically:
//   G = phi_factor(m1,m2,m3) * sum_t w_t Pbar_{l1|m1|} Pbar_{l2|m2|} Pbar_{l3|m3|}
// phi_factor is exact (Kronecker deltas); theta sum uses constexpr GL nodes.
// Matches reference to ~1e-15 rel. Exact-zero terms are pruned at compile time.
// ===========================================================================
constexpr double CPI = 3.14159265358979323846;

constexpr double csqrt(double x) {
  if (x <= 0.0) return 0.0;
  double y = x > 1.0 ? x : 1.0;
  for (int i = 0; i < 48; ++i) y = 0.5 * (y + x / y);
  return y;
}
constexpr double ccos(double x) {
  double r = x;
  while (r > CPI)  r -= 2.0 * CPI;
  while (r < -CPI) r += 2.0 * CPI;
  double r2 = r * r, term = 1.0, sum = 1.0;
  for (int i = 1; i <= 26; ++i) { term *= -r2 / ((2.0 * i - 1.0) * (2.0 * i)); sum += term; }
  return sum;
}
constexpr int iabs_c(int x) { return x < 0 ? -x : x; }

struct GLQ { double x[16]; double w[16]; };
constexpr GLQ build_gl() {
  GLQ g{};
  const int n = 16;
  for (int i = 0; i < n; ++i) {
    double x = ccos(CPI * (i + 0.75) / (n + 0.5));
    double p1 = 0.0, dp = 1.0;
    for (int it = 0; it < 40; ++it) {
      double p0 = 1.0; p1 = x;
      for (int k = 2; k <= n; ++k) { double p2 = ((2.0*k-1.0)*x*p1 - (k-1.0)*p0)/k; p0 = p1; p1 = p2; }
      dp = n * (x*p1 - p0) / (x*x - 1.0);
      x -= p1 / dp;
    }
    { double p0 = 1.0; p1 = x;
      for (int k = 2; k <= n; ++k) { double p2 = ((2.0*k-1.0)*x*p1 - (k-1.0)*p0)/k; p0 = p1; p1 = p2; }
      dp = n * (x*p1 - p0) / (x*x - 1.0); }
    g.x[i] = x;
    g.w[i] = 2.0 / ((1.0 - x*x) * dp * dp);
  }
  return g;
}
constexpr GLQ QG = build_gl();

struct PTab { double v[4][4][16]; };   // [l][m][node], fully-normalized Pbar
constexpr PTab build_pbar() {
  PTab T{};
  for (int t = 0; t < 16; ++t) {
    double ct = QG.x[t];
    double st = csqrt(1.0 - ct * ct);
    double P[4][4] = {};
    P[0][0] = csqrt(1.0 / (4.0 * CPI));
    for (int m = 1; m <= 3; ++m)
      P[m][m] = csqrt((2.0*m + 1.0) / (2.0*m)) * st * P[m-1][m-1];
    for (int m = 0; m <= 3; ++m) {
      if (m + 1 <= 3) P[m+1][m] = csqrt(2.0*m + 3.0) * ct * P[m][m];
      for (int l = m + 2; l <= 3; ++l) {
        double aa = csqrt((4.0*(double)l*l - 1.0) / ((double)l*l - (double)m*m));
        double bb = csqrt(((double)(l-1)*(l-1) - (double)m*m) / (4.0*(double)(l-1)*(l-1) - 1.0));
        P[l][m] = aa * (ct * P[l-1][m] - bb * P[l-2][m]);
      }
    }
    for (int l = 0; l < 4; ++l)
      for (int m = 0; m <= l; ++m) T.v[l][m][t] = P[l][m];
  }
  return T;
}
constexpr PTab PT = build_pbar();

// exact phi integral of f1*f2*f3, f = 1 (m=0) | sqrt2*cos(mphi) (m>0) | sqrt2*sin(|m|phi) (m<0)
constexpr double phi_int(int m1, int m2, int m3) {
  const double SQ2 = 1.41421356237309504880;
  int neg = (m1 < 0) + (m2 < 0) + (m3 < 0);
  if (neg & 1) return 0.0;
  int a = iabs_c(m1), b = iabs_c(m2), c = iabs_c(m3);
  int nz = (a > 0) + (b > 0) + (c > 0);
  if (nz == 0) return 2.0 * CPI;
  if (nz == 1) return 0.0;
  if (nz == 2) {
    int p = 0, q = 0;
    if (a == 0) { p = b; q = c; } else if (b == 0) { p = a; q = c; } else { p = a; q = b; }
    return (p == q) ? 2.0 * CPI : 0.0;
  }
  if (neg == 0) {  // cos cos cos
    double v = 0.0;
    if (iabs_c(a - b) == c && a != b) v += 1.0;
    if (a + b == c) v += 1.0;
    return SQ2 * CPI * v;
  }
  // one cos (freq p), two sin (freqs q, r)
  int p, q, r;
  if (m1 > 0)      { p = a; q = b; r = c; }
  else if (m2 > 0) { p = b; q = a; r = c; }
  else             { p = c; q = a; r = b; }
  double v = 0.0;
  if (q != r && p == iabs_c(q - r)) v += 1.0;
  if (p == q + r) v -= 1.0;
  return SQ2 * CPI * v;
}

constexpr bool path_ok(int l1, int l2, int l3) {
  int lo = l1 > l2 ? l1 - l2 : l2 - l1;
  return l3 >= lo && l3 <= l1 + l2 && (((l1 + l2 + l3) & 1) == 0);
}
constexpr bool term_ok(int m1, int m2, int m3) {
  int aa = iabs_c(m1), bb = iabs_c(m2), cc = iabs_c(m3);
  int neg = (m1 < 0) + (m2 < 0) + (m3 < 0);
  if (neg & 1) return false;
  return (aa + bb == cc) || (bb + cc == aa) || (cc + aa == bb);
}
constexpr int count_paths() {
  int n = 0;
  for (int l1 = 0; l1 < 4; ++l1) for (int l2 = 0; l2 < 4; ++l2) for (int l3 = 0; l3 < 4; ++l3)
    if (path_ok(l1, l2, l3)) ++n;
  return n;
}
constexpr int NPATHS = count_paths();   // 23
constexpr int NTMAX  = 512;

constexpr double term_g(int l1, int m1, int l2, int m2, int l3, int m3) {
  double ph = phi_int(m1, m2, m3);
  if (ph == 0.0) return 0.0;
  int a = iabs_c(m1), b = iabs_c(m2), c = iabs_c(m3);
  double s = 0.0;
  for (int t = 0; t < 16; ++t)
    s += QG.w[t] * PT.v[l1][a][t] * PT.v[l2][b][t] * PT.v[l3][c][t];
  double g = ph * s;
  double fan = (l3 == 0) ? 4.0 : (l3 == 1 ? 6.0 : (l3 == 2 ? 7.0 : 6.0));
  return g * csqrt((2.0 * (double)l3 + 1.0) / fan);
}

struct TermG { float g; unsigned char i, j, k, p; };
struct PathT { unsigned char l1, l2, l3; };
struct TGAll { TermG t[NTMAX]; int n; };
constexpr TGAll build_all() {
  TGAll r{};
  r.n = 0;
  int p = 0;
  for (int l1 = 0; l1 < 4; ++l1) for (int l2 = 0; l2 < 4; ++l2) for (int l3 = 0; l3 < 4; ++l3) {
    if (!path_ok(l1, l2, l3)) continue;
    for (int m1 = -l1; m1 <= l1; ++m1) for (int m2 = -l2; m2 <= l2; ++m2) for (int m3 = -l3; m3 <= l3; ++m3) {
      if (!term_ok(m1, m2, m3)) continue;
      double g = term_g(l1, m1, l2, m2, l3, m3);
      if (g > 1e-10 || g < -1e-10) {
        r.t[r.n].g = (float)g;
        r.t[r.n].i = (unsigned char)(l1 * l1 + l1 + m1);
        r.t[r.n].j = (unsigned char)(l2 * l2 + l2 + m2);
        r.t[r.n].k = (unsigned char)(l3 * l3 + l3 + m3);
        r.t[r.n].p = (unsigned char)p;
        ++r.n;
      }
    }
    ++p;
  }
  return r;
}
constexpr TGAll TGA = build_all();
constexpr int NNZ = TGA.n;

constexpr std::array<PathT, NPATHS> build_paths() {
  std::array<PathT, NPATHS> a{};
  int n = 0;
  for (int l1 = 0; l1 < 4; ++l1) for (int l2 = 0; l2 < 4; ++l2) for (int l3 = 0; l3 < 4; ++l3)
    if (path_ok(l1, l2, l3)) a[n++] = PathT{(unsigned char)l1, (unsigned char)l2, (unsigned char)l3};
  return a;
}
constexpr auto PATHS_ARR = build_paths();

// Fold expansion: all indices and g-coefficients are compile-time constants;
// t/h/wgv stay register-resident, g becomes an inline literal.
template <size_t... Is>
__device__ __forceinline__ void gaunt_terms(std::index_sequence<Is...>,
    float* __restrict__ t, const float* __restrict__ h,
    const float* __restrict__ wgv) {
  ((t[TGA.t[Is].k] = fmaf(TGA.t[Is].g * wgv[TGA.t[Is].p],
                          h[TGA.t[Is].i] * h[TGA.t[Is].j],
                          t[TGA.t[Is].k])), ...);
}
template <size_t... Ps>
__device__ __forceinline__ void load_wgv(std::index_sequence<Ps...>,
    float* __restrict__ wgv, const float* __restrict__ wg, int c) {
  ((wgv[Ps] = wg[(size_t)(((int)PATHS_ARR[Ps].l1 * 4 + (int)PATHS_ARR[Ps].l2) * 4
                          + (int)PATHS_ARR[Ps].l3) * CHID + c]), ...);
}

// ---------------------------------------------------------------------------
// Transpose + f32->bf16 convert: src [nmat][R][C] f32 -> dst [nmat][C][R] bf16
// ---------------------------------------------------------------------------
__global__ __launch_bounds__(256) void transpose_bf16_kernel(
    const float* __restrict__ src, u16* __restrict__ dst, int R, int C) {
  __shared__ float tile[32][33];
  int mat = blockIdx.z;
  int r0 = blockIdx.y * 32, c0 = blockIdx.x * 32;
  const float* s = src + (size_t)mat * R * C;
  u16* d = dst + (size_t)mat * R * C;
  int tx = threadIdx.x & 31, ty = threadIdx.x >> 5;
  for (int rr = ty; rr < 32; rr += 8)
    tile[rr][tx] = s[(size_t)(r0 + rr) * C + (c0 + tx)];
  __syncthreads();
  for (int cc = ty; cc < 32; cc += 8)
    d[(size_t)(c0 + cc) * R + (r0 + tx)] = f2bf(tile[tx][cc]);
}

// ---------------------------------------------------------------------------
// Equivariant layernorm: center l=0 over C, RMS over (16,384), per-degree
// affine, norm_b on l=0 only. Writes bf16 [n][16][384].
// ---------------------------------------------------------------------------
__global__ __launch_bounds__(256) void norm_kernel(
    const float* __restrict__ x, const float* __restrict__ nw,
    const float* __restrict__ nb, u16* __restrict__ xnb) {
  int n = blockIdx.x, tid = threadIdx.x;
  const float* xr = x + (size_t)n * (L2DIM * CIN);
  __shared__ float xs[L2DIM * CIN];
  __shared__ float2 red[4];
  float4 v[6];
  float ssq = 0.f;
#pragma unroll
  for (int q = 0; q < 6; ++q) {
    v[q] = reinterpret_cast<const float4*>(xr)[tid * 6 + q];
    ssq += v[q].x*v[q].x + v[q].y*v[q].y + v[q].z*v[q].z + v[q].w*v[q].w;
    reinterpret_cast<float4*>(xs)[tid * 6 + q] = v[q];
  }
  __syncthreads();
  float m0p = 0.f;
  for (int c = tid; c < CIN; c += 256) m0p += xs[c];
  float a = m0p, b = ssq;
#pragma unroll
  for (int off = 32; off > 0; off >>= 1) { a += __shfl_down(a, off, 64); b += __shfl_down(b, off, 64); }
  int lane = tid & 63, wid = tid >> 6;
  if (lane == 0) red[wid] = make_float2(a, b);
  __syncthreads();
  float sum0 = red[0].x + red[1].x + red[2].x + red[3].x;
  float ssqt = red[0].y + red[1].y + red[2].y + red[3].y;
  float mean0 = sum0 * (1.0f / CIN);
  float ss = ssqt - (float)CIN * mean0 * mean0;
  float rstd = rsqrtf(ss * (1.0f / (L2DIM * CIN)) + 1e-5f);

  int lm = tid >> 4;
  int l = LOF(lm);
  bool row0 = (lm == 0);
  int cbase = (tid & 15) * 24;
  u16* orow = xnb + (size_t)n * (L2DIM * CIN) + (size_t)tid * 24;
#pragma unroll
  for (int q = 0; q < 6; ++q) {
    int c = cbase + q * 4;
    float4 w4 = *reinterpret_cast<const float4*>(&nw[l * CIN + c]);
    float4 b4 = row0 ? *reinterpret_cast<const float4*>(&nb[c]) : make_float4(0,0,0,0);
    float sub = row0 ? mean0 : 0.f;
    float o0 = (v[q].x - sub) * rstd * w4.x + b4.x;
    float o1 = (v[q].y - sub) * rstd * w4.y + b4.y;
    float o2 = (v[q].z - sub) * rstd * w4.z + b4.z;
    float o3 = (v[q].w - sub) * rstd * w4.w + b4.w;
    ushort4 pk;
    pk.x = f2bf(o0); pk.y = f2bf(o1); pk.z = f2bf(o2); pk.w = f2bf(o3);
    *reinterpret_cast<ushort4*>(&orow[q * 4]) = pk;
  }
}

// ---------------------------------------------------------------------------
// Per-degree GEMM with MFMA 16x16x32 bf16 (unchanged).
// ---------------------------------------------------------------------------
template <int KD, int ND, bool SECOND>
__global__ __launch_bounds__(256) void so3_gemm_kernel(
    const u16* __restrict__ A, const u16* __restrict__ BT,
    const float* __restrict__ bias, const float* __restrict__ resid,
    u16* __restrict__ outb, float* __restrict__ outf) {
  int l = blockIdx.z;
  int twol1 = 2 * l + 1;
  int mtiles = (NNODES * twol1) >> 6;
  if ((int)blockIdx.x >= mtiles) return;
  int col0 = blockIdx.y * 128;
  int tid = threadIdx.x, lane = tid & 63, wid = tid >> 6;
  int wm = wid >> 1, wn = wid & 1;

  __shared__ u16 Asm[64 * 64];
  __shared__ u16 Bsm[128 * 64];

  const u16* asrc[2];
#pragma unroll
  for (int rr = 0; rr < 2; ++rr) {
    int r = wid * 16 + rr * 8 + (lane >> 3);
    int Rg = blockIdx.x * 64 + r;
    int node = Rg / twol1;
    int lm = l * l + (Rg - node * twol1);
    asrc[rr] = A + (size_t)(node * L2DIM + lm) * KD + ((lane & 7) ^ (r & 7)) * 8;
  }
  const u16* bsrc[4];
#pragma unroll
  for (int rr = 0; rr < 4; ++rr) {
    int r = wid * 32 + rr * 8 + (lane >> 3);
    int colg = col0 + r;
    bsrc[rr] = BT + (size_t)(l * ND + colg) * KD + ((lane & 7) ^ (r & 7)) * 8;
  }

  f32x4 acc[2][4];
#pragma unroll
  for (int i = 0; i < 2; ++i)
#pragma unroll
    for (int j = 0; j < 4; ++j) acc[i][j] = (f32x4){0.f, 0.f, 0.f, 0.f};

  for (int kt = 0; kt < KD / 64; ++kt) {
#pragma unroll
    for (int rr = 0; rr < 2; ++rr)
      __builtin_amdgcn_global_load_lds(
          (const __attribute__((address_space(1))) void*)(asrc[rr] + kt * 64),
          (__attribute__((address_space(3))) void*)(&Asm[wid * 1024 + rr * 512]),
          16, 0, 0);
#pragma unroll
    for (int rr = 0; rr < 4; ++rr)
      __builtin_amdgcn_global_load_lds(
          (const __attribute__((address_space(1))) void*)(bsrc[rr] + kt * 64),
          (__attribute__((address_space(3))) void*)(&Bsm[wid * 2048 + rr * 512]),
          16, 0, 0);
    __syncthreads();
#pragma unroll
    for (int ks = 0; ks < 2; ++ks) {
      short8 af[2], bfv[4];
#pragma unroll
      for (int mf = 0; mf < 2; ++mf) {
        int row = wm * 32 + mf * 16 + (lane & 15);
        int slot = (ks * 4 + (lane >> 4)) ^ (row & 7);
        af[mf] = *reinterpret_cast<const short8*>(&Asm[row * 64 + slot * 8]);
      }
#pragma unroll
      for (int nf = 0; nf < 4; ++nf) {
        int brow = wn * 64 + nf * 16 + (lane & 15);
        int slot = (ks * 4 + (lane >> 4)) ^ (brow & 7);
        bfv[nf] = *reinterpret_cast<const short8*>(&Bsm[brow * 64 + slot * 8]);
      }
#pragma unroll
      for (int mf = 0; mf < 2; ++mf)
#pragma unroll
        for (int nf = 0; nf < 4; ++nf)
          acc[mf][nf] = __builtin_amdgcn_mfma_f32_16x16x32_bf16(af[mf], bfv[nf], acc[mf][nf], 0, 0, 0);
    }
    __syncthreads();
  }

#pragma unroll
  for (int mf = 0; mf < 2; ++mf) {
#pragma unroll
    for (int jj = 0; jj < 4; ++jj) {
      int Rg = blockIdx.x * 64 + wm * 32 + mf * 16 + (lane >> 4) * 4 + jj;
      int node = Rg / twol1;
      int lm = l * l + (Rg - node * twol1);
      size_t rowoff = (size_t)(node * L2DIM + lm);
#pragma unroll
      for (int nf = 0; nf < 4; ++nf) {
        int colg = col0 + wn * 64 + nf * 16 + (lane & 15);
        float vv = acc[mf][nf][jj];
        if (l == 0) vv += bias[colg];
        if (!SECOND) {
          outb[rowoff * ND + colg] = f2bf(vv);
        } else {
          outf[rowoff * ND + colg] = vv + resid[rowoff * ND + colg];
        }
      }
    }
  }
}

// ---------------------------------------------------------------------------
// Depthwise Gaunt tensor product, fully static expansion with compile-time
// coefficients (no table loads). Thread = (node, channel).
// ---------------------------------------------------------------------------
__global__ __launch_bounds__(256, 2) void gaunt_kernel(
    const u16* __restrict__ hb, const float* __restrict__ wg,
    u16* __restrict__ tb) {
  int n = blockIdx.x, c = threadIdx.x;
  const u16* hr = hb + (size_t)n * (L2DIM * CHID) + c;
  float h[16];
#pragma unroll
  for (int i = 0; i < 16; ++i) h[i] = bf2f(hr[i * CHID]);

  float wgv[NPATHS];
  load_wgv(std::make_index_sequence<NPATHS>{}, wgv, wg, c);

  float t[16];
#pragma unroll
  for (int k = 0; k < 16; ++k) t[k] = 0.f;

  gaunt_terms(std::make_index_sequence<NNZ>{}, t, h, wgv);

  u16* tr = tb + (size_t)n * (L2DIM * CHID) + c;
#pragma unroll
  for (int k = 0; k < 16; ++k) tr[k * CHID] = f2bf(t[k]);
}

// ---------------------------------------------------------------------------
extern "C" void kernel_launch(void* const* d_in, const int* in_sizes, int n_in,
                              void* d_out, int out_size, void* d_ws, size_t ws_size,
                              hipStream_t stream) {
  const float* inputs = (const float*)d_in[0];
  // d_in[1] = batch (unused: drop paths disabled)
  const float* norm_w = (const float*)d_in[2];
  const float* norm_b = (const float*)d_in[3];
  const float* w1     = (const float*)d_in[4];
  const float* b1     = (const float*)d_in[5];
  const float* wga    = (const float*)d_in[6];
  const float* w2     = (const float*)d_in[7];
  const float* b2     = (const float*)d_in[8];
  float* out = (float*)d_out;

  uint8_t* ws = (uint8_t*)d_ws;
  u16*   w1t = (u16*)(ws + 16384);          // [4][256][384] bf16, 768 KB
  u16*   w2t = (u16*)(ws + 802816);         // [4][384][256] bf16, 768 KB
  u16*   xnb = (u16*)(ws + 1589248);        // [2048][16][384] bf16, 24 MB
  u16*   tb  = xnb;                         // reuse after GEMM1 consumed xnb
  u16*   hb  = (u16*)(ws + 26755072);       // [2048][16][256] bf16, 16 MB

  transpose_bf16_kernel<<<dim3(8, 12, 4), 256, 0, stream>>>(w1, w1t, 384, 256);
  transpose_bf16_kernel<<<dim3(12, 8, 4), 256, 0, stream>>>(w2, w2t, 256, 384);
  norm_kernel<<<NNODES, 256, 0, stream>>>(inputs, norm_w, norm_b, xnb);
  so3_gemm_kernel<CIN, CHID, false><<<dim3(224, 2, 4), 256, 0, stream>>>(
      xnb, w1t, b1, nullptr, hb, nullptr);
  gaunt_kernel<<<NNODES, 256, 0, stream>>>(hb, wga, tb);
  so3_gemm_kernel<CHID, CIN, true><<<dim3(224, 3, 4), 256, 0, stream>>>(
      tb, w2t, b2, inputs, nullptr, out);
}

// Round 5
// 92.136 us; speedup vs baseline: 4.6926x; 1.0108x over previous
//
#include <hip/hip_runtime.h>
#include <stdint.h>
#include <math.h>
#include <array>
#include <utility>

#ifndef M_PI
#define M_PI 3.14159265358979323846
#endif

#define NNODES 2048
#define L2DIM  16
#define CIN    384
#define CHID   256

typedef __attribute__((ext_vector_type(8))) short short8;
typedef __attribute__((ext_vector_type(4))) float f32x4;
typedef unsigned short u16;
typedef unsigned int   u32;

#define LOF(i) ((i) < 1 ? 0 : ((i) < 4 ? 1 : ((i) < 9 ? 2 : 3)))

static __device__ __forceinline__ u16 f2bf(float f) {
  u32 u = __builtin_bit_cast(u32, f);
  u = u + 0x7FFFu + ((u >> 16) & 1u);   // RNE
  return (u16)(u >> 16);
}
static __device__ __forceinline__ float bf2f(u16 b) {
  u32 u = ((u32)b) << 16;
  return __builtin_bit_cast(float, u);
}

// ===========================================================================
// COMPILE-TIME Gaunt coefficients (validated round 3: absmax 0.0625).
// ===========================================================================
constexpr double CPI = 3.14159265358979323846;

constexpr double csqrt(double x) {
  if (x <= 0.0) return 0.0;
  double y = x > 1.0 ? x : 1.0;
  for (int i = 0; i < 48; ++i) y = 0.5 * (y + x / y);
  return y;
}
constexpr double ccos(double x) {
  double r = x;
  while (r > CPI)  r -= 2.0 * CPI;
  while (r < -CPI) r += 2.0 * CPI;
  double r2 = r * r, term = 1.0, sum = 1.0;
  for (int i = 1; i <= 26; ++i) { term *= -r2 / ((2.0 * i - 1.0) * (2.0 * i)); sum += term; }
  return sum;
}
constexpr int iabs_c(int x) { return x < 0 ? -x : x; }

struct GLQ { double x[16]; double w[16]; };
constexpr GLQ build_gl() {
  GLQ g{};
  const int n = 16;
  for (int i = 0; i < n; ++i) {
    double x = ccos(CPI * (i + 0.75) / (n + 0.5));
    double p1 = 0.0, dp = 1.0;
    for (int it = 0; it < 40; ++it) {
      double p0 = 1.0; p1 = x;
      for (int k = 2; k <= n; ++k) { double p2 = ((2.0*k-1.0)*x*p1 - (k-1.0)*p0)/k; p0 = p1; p1 = p2; }
      dp = n * (x*p1 - p0) / (x*x - 1.0);
      x -= p1 / dp;
    }
    { double p0 = 1.0; p1 = x;
      for (int k = 2; k <= n; ++k) { double p2 = ((2.0*k-1.0)*x*p1 - (k-1.0)*p0)/k; p0 = p1; p1 = p2; }
      dp = n * (x*p1 - p0) / (x*x - 1.0); }
    g.x[i] = x;
    g.w[i] = 2.0 / ((1.0 - x*x) * dp * dp);
  }
  return g;
}
constexpr GLQ QG = build_gl();

struct PTab { double v[4][4][16]; };
constexpr PTab build_pbar() {
  PTab T{};
  for (int t = 0; t < 16; ++t) {
    double ct = QG.x[t];
    double st = csqrt(1.0 - ct * ct);
    double P[4][4] = {};
    P[0][0] = csqrt(1.0 / (4.0 * CPI));
    for (int m = 1; m <= 3; ++m)
      P[m][m] = csqrt((2.0*m + 1.0) / (2.0*m)) * st * P[m-1][m-1];
    for (int m = 0; m <= 3; ++m) {
      if (m + 1 <= 3) P[m+1][m] = csqrt(2.0*m + 3.0) * ct * P[m][m];
      for (int l = m + 2; l <= 3; ++l) {
        double aa = csqrt((4.0*(double)l*l - 1.0) / ((double)l*l - (double)m*m));
        double bb = csqrt(((double)(l-1)*(l-1) - (double)m*m) / (4.0*(double)(l-1)*(l-1) - 1.0));
        P[l][m] = aa * (ct * P[l-1][m] - bb * P[l-2][m]);
      }
    }
    for (int l = 0; l < 4; ++l)
      for (int m = 0; m <= l; ++m) T.v[l][m][t] = P[l][m];
  }
  return T;
}
constexpr PTab PT = build_pbar();

constexpr double phi_int(int m1, int m2, int m3) {
  const double SQ2 = 1.41421356237309504880;
  int neg = (m1 < 0) + (m2 < 0) + (m3 < 0);
  if (neg & 1) return 0.0;
  int a = iabs_c(m1), b = iabs_c(m2), c = iabs_c(m3);
  int nz = (a > 0) + (b > 0) + (c > 0);
  if (nz == 0) return 2.0 * CPI;
  if (nz == 1) return 0.0;
  if (nz == 2) {
    int p = 0, q = 0;
    if (a == 0) { p = b; q = c; } else if (b == 0) { p = a; q = c; } else { p = a; q = b; }
    return (p == q) ? 2.0 * CPI : 0.0;
  }
  if (neg == 0) {
    double v = 0.0;
    if (iabs_c(a - b) == c && a != b) v += 1.0;
    if (a + b == c) v += 1.0;
    return SQ2 * CPI * v;
  }
  int p = 0, q = 0, r = 0;
  if (m1 > 0)      { p = a; q = b; r = c; }
  else if (m2 > 0) { p = b; q = a; r = c; }
  else             { p = c; q = a; r = b; }
  double v = 0.0;
  if (q != r && p == iabs_c(q - r)) v += 1.0;
  if (p == q + r) v -= 1.0;
  return SQ2 * CPI * v;
}

constexpr bool path_ok(int l1, int l2, int l3) {
  int lo = l1 > l2 ? l1 - l2 : l2 - l1;
  return l3 >= lo && l3 <= l1 + l2 && (((l1 + l2 + l3) & 1) == 0);
}
constexpr bool term_ok(int m1, int m2, int m3) {
  int aa = iabs_c(m1), bb = iabs_c(m2), cc = iabs_c(m3);
  int neg = (m1 < 0) + (m2 < 0) + (m3 < 0);
  if (neg & 1) return false;
  return (aa + bb == cc) || (bb + cc == aa) || (cc + aa == bb);
}
constexpr int count_paths() {
  int n = 0;
  for (int l1 = 0; l1 < 4; ++l1) for (int l2 = 0; l2 < 4; ++l2) for (int l3 = 0; l3 < 4; ++l3)
    if (path_ok(l1, l2, l3)) ++n;
  return n;
}
constexpr int NPATHS = count_paths();   // 23
constexpr int NTMAX  = 512;

constexpr double term_g(int l1, int m1, int l2, int m2, int l3, int m3) {
  double ph = phi_int(m1, m2, m3);
  if (ph == 0.0) return 0.0;
  int a = iabs_c(m1), b = iabs_c(m2), c = iabs_c(m3);
  double s = 0.0;
  for (int t = 0; t < 16; ++t)
    s += QG.w[t] * PT.v[l1][a][t] * PT.v[l2][b][t] * PT.v[l3][c][t];
  double g = ph * s;
  double fan = (l3 == 0) ? 4.0 : (l3 == 1 ? 6.0 : (l3 == 2 ? 7.0 : 6.0));
  return g * csqrt((2.0 * (double)l3 + 1.0) / fan);
}

struct TermG { float g; unsigned char i, j, k, p; };
struct PathT { unsigned char l1, l2, l3; };
struct TGAll { TermG t[NTMAX]; int n; };
constexpr TGAll build_all() {
  TGAll r{};
  r.n = 0;
  int p = 0;
  for (int l1 = 0; l1 < 4; ++l1) for (int l2 = 0; l2 < 4; ++l2) for (int l3 = 0; l3 < 4; ++l3) {
    if (!path_ok(l1, l2, l3)) continue;
    for (int m1 = -l1; m1 <= l1; ++m1) for (int m2 = -l2; m2 <= l2; ++m2) for (int m3 = -l3; m3 <= l3; ++m3) {
      if (!term_ok(m1, m2, m3)) continue;
      double g = term_g(l1, m1, l2, m2, l3, m3);
      if (g > 1e-10 || g < -1e-10) {
        r.t[r.n].g = (float)g;
        r.t[r.n].i = (unsigned char)(l1 * l1 + l1 + m1);
        r.t[r.n].j = (unsigned char)(l2 * l2 + l2 + m2);
        r.t[r.n].k = (unsigned char)(l3 * l3 + l3 + m3);
        r.t[r.n].p = (unsigned char)p;
        ++r.n;
      }
    }
    ++p;
  }
  return r;
}
constexpr TGAll TGA = build_all();
constexpr int NNZ = TGA.n;

constexpr std::array<PathT, NPATHS> build_paths() {
  std::array<PathT, NPATHS> a{};
  int n = 0;
  for (int l1 = 0; l1 < 4; ++l1) for (int l2 = 0; l2 < 4; ++l2) for (int l3 = 0; l3 < 4; ++l3)
    if (path_ok(l1, l2, l3)) a[n++] = PathT{(unsigned char)l1, (unsigned char)l2, (unsigned char)l3};
  return a;
}
constexpr auto PATHS_ARR = build_paths();

template <size_t... Is>
__device__ __forceinline__ void gaunt_terms(std::index_sequence<Is...>,
    float* __restrict__ t, const float* __restrict__ h,
    const float* __restrict__ wgv) {
  ((t[TGA.t[Is].k] = fmaf(TGA.t[Is].g * wgv[TGA.t[Is].p],
                          h[TGA.t[Is].i] * h[TGA.t[Is].j],
                          t[TGA.t[Is].k])), ...);
}
template <size_t... Ps>
__device__ __forceinline__ void load_wgv(std::index_sequence<Ps...>,
    float* __restrict__ wgv, const float* __restrict__ wg, int c) {
  ((wgv[Ps] = wg[(size_t)(((int)PATHS_ARR[Ps].l1 * 4 + (int)PATHS_ARR[Ps].l2) * 4
                          + (int)PATHS_ARR[Ps].l3) * CHID + c]), ...);
}

// ---------------------------------------------------------------------------
// Merged weight transpose + f32->bf16: z<4 -> w1 mats (384x256),
// z>=4 -> w2 mats (256x384). dst is [C][R] bf16 per matrix.
// ---------------------------------------------------------------------------
__global__ __launch_bounds__(256) void transpose_bf16_kernel(
    const float* __restrict__ w1, const float* __restrict__ w2,
    u16* __restrict__ w1t, u16* __restrict__ w2t) {
  __shared__ float tile[32][33];
  int z = blockIdx.z;
  int R = z < 4 ? 384 : 256, C = z < 4 ? 256 : 384;
  int r0 = blockIdx.y * 32, c0 = blockIdx.x * 32;
  if (r0 >= R || c0 >= C) return;
  const float* s = (z < 4 ? w1 : w2) + (size_t)(z & 3) * R * C;
  u16* d = (z < 4 ? w1t : w2t) + (size_t)(z & 3) * R * C;
  int tx = threadIdx.x & 31, ty = threadIdx.x >> 5;
  for (int rr = ty; rr < 32; rr += 8)
    tile[rr][tx] = s[(size_t)(r0 + rr) * C + (c0 + tx)];
  __syncthreads();
  for (int cc = ty; cc < 32; cc += 8)
    d[(size_t)(c0 + cc) * R + (r0 + tx)] = f2bf(tile[tx][cc]);
}

// ---------------------------------------------------------------------------
// Equivariant layernorm, LDS-free data path: threads 0-15 own row 0 (l=0)
// in registers, so mean0 folds into the same block reduction as ssq.
// ---------------------------------------------------------------------------
__global__ __launch_bounds__(256) void norm_kernel(
    const float* __restrict__ x, const float* __restrict__ nw,
    const float* __restrict__ nb, u16* __restrict__ xnb) {
  int n = blockIdx.x, tid = threadIdx.x;
  const float* xr = x + (size_t)n * (L2DIM * CIN);
  __shared__ float2 red[4];
  float4 v[6];
  float ssq = 0.f, m0p = 0.f;
#pragma unroll
  for (int q = 0; q < 6; ++q) {
    v[q] = reinterpret_cast<const float4*>(xr)[tid * 6 + q];
    ssq += v[q].x*v[q].x + v[q].y*v[q].y + v[q].z*v[q].z + v[q].w*v[q].w;
  }
  if (tid < 16) {   // these 16 threads hold exactly row 0 (16*24 = 384)
#pragma unroll
    for (int q = 0; q < 6; ++q) m0p += v[q].x + v[q].y + v[q].z + v[q].w;
  }
  float a = m0p, b = ssq;
#pragma unroll
  for (int off = 32; off > 0; off >>= 1) { a += __shfl_down(a, off, 64); b += __shfl_down(b, off, 64); }
  int lane = tid & 63, wid = tid >> 6;
  if (lane == 0) red[wid] = make_float2(a, b);
  __syncthreads();
  float sum0 = red[0].x + red[1].x + red[2].x + red[3].x;
  float ssqt = red[0].y + red[1].y + red[2].y + red[3].y;
  float mean0 = sum0 * (1.0f / CIN);
  float ss = ssqt - (float)CIN * mean0 * mean0;
  float rstd = rsqrtf(ss * (1.0f / (L2DIM * CIN)) + 1e-5f);

  int lm = tid >> 4;
  int l = LOF(lm);
  bool row0 = (lm == 0);
  int cbase = (tid & 15) * 24;
  u16* orow = xnb + (size_t)n * (L2DIM * CIN) + (size_t)tid * 24;
#pragma unroll
  for (int q = 0; q < 6; ++q) {
    int c = cbase + q * 4;
    float4 w4 = *reinterpret_cast<const float4*>(&nw[l * CIN + c]);
    float4 b4 = row0 ? *reinterpret_cast<const float4*>(&nb[c]) : make_float4(0,0,0,0);
    float sub = row0 ? mean0 : 0.f;
    float o0 = (v[q].x - sub) * rstd * w4.x + b4.x;
    float o1 = (v[q].y - sub) * rstd * w4.y + b4.y;
    float o2 = (v[q].z - sub) * rstd * w4.z + b4.z;
    float o3 = (v[q].w - sub) * rstd * w4.w + b4.w;
    ushort4 pk;
    pk.x = f2bf(o0); pk.y = f2bf(o1); pk.z = f2bf(o2); pk.w = f2bf(o3);
    *reinterpret_cast<ushort4*>(&orow[q * 4]) = pk;
  }
}

// ---------------------------------------------------------------------------
// Per-degree GEMM, full-width blocks: BM=64, BN=ND (256 or 384), BK=64,
// 512 threads = 8 waves (2 M x 4 N), wave tile 32 x ND/4.
// A staged once per K-tile (no col-block redundancy).
// ---------------------------------------------------------------------------
template <int KD, int ND, bool SECOND>
__global__ __launch_bounds__(512) void so3_gemm_kernel(
    const u16* __restrict__ A, const u16* __restrict__ BT,
    const float* __restrict__ bias, const float* __restrict__ resid,
    u16* __restrict__ outb, float* __restrict__ outf) {
  constexpr int NFRAG = ND / 64;            // 4 (ND=256) or 6 (ND=384) frags/wave
  constexpr int WN_T = ND / 4;              // wave tile N (64 or 96)
  static_assert((ND % 64) == 0 && NFRAG * 16 == WN_T, "");
  int l = blockIdx.z;
  int twol1 = 2 * l + 1;
  int mtiles = (NNODES * twol1) >> 6;
  if ((int)blockIdx.x >= mtiles) return;
  int tid = threadIdx.x, lane = tid & 63, wid = tid >> 6;
  int wm = wid >> 2, wn = wid & 3;

  __shared__ u16 Asm[64 * 64];          //  8 KB
  __shared__ u16 Bsm[ND * 64];          // 32/48 KB

  // A staging: one global_load_lds covers the 64x64 tile (512 thr x 16 B).
  int ar = tid >> 3;                    // row 0..63
  const u16* asrc;
  {
    int Rg = blockIdx.x * 64 + ar;
    int node = Rg / twol1;
    int lm = l * l + (Rg - node * twol1);
    asrc = A + (size_t)(node * L2DIM + lm) * KD + ((tid & 7) ^ (ar & 7)) * 8;
  }
  // B staging: ND/64 insts, inst i covers rows i*64..i*64+63.
  const u16* bsrc[ND / 64];
#pragma unroll
  for (int i = 0; i < ND / 64; ++i) {
    int r = i * 64 + (tid >> 3);
    bsrc[i] = BT + (size_t)(l * ND + r) * KD + ((tid & 7) ^ (r & 7)) * 8;
  }

  f32x4 acc[2][NFRAG];
#pragma unroll
  for (int i = 0; i < 2; ++i)
#pragma unroll
    for (int j = 0; j < NFRAG; ++j) acc[i][j] = (f32x4){0.f, 0.f, 0.f, 0.f};

  for (int kt = 0; kt < KD / 64; ++kt) {
    __builtin_amdgcn_global_load_lds(
        (const __attribute__((address_space(1))) void*)(asrc + kt * 64),
        (__attribute__((address_space(3))) void*)(&Asm[wid * 512]),
        16, 0, 0);
#pragma unroll
    for (int i = 0; i < ND / 64; ++i)
      __builtin_amdgcn_global_load_lds(
          (const __attribute__((address_space(1))) void*)(bsrc[i] + kt * 64),
          (__attribute__((address_space(3))) void*)(&Bsm[i * 4096 + wid * 512]),
          16, 0, 0);
    __syncthreads();
#pragma unroll
    for (int ks = 0; ks < 2; ++ks) {
      short8 af[2], bfv[NFRAG];
#pragma unroll
      for (int mf = 0; mf < 2; ++mf) {
        int row = wm * 32 + mf * 16 + (lane & 15);
        int slot = (ks * 4 + (lane >> 4)) ^ (row & 7);
        af[mf] = *reinterpret_cast<const short8*>(&Asm[row * 64 + slot * 8]);
      }
#pragma unroll
      for (int nf = 0; nf < NFRAG; ++nf) {
        int brow = wn * WN_T + nf * 16 + (lane & 15);
        int slot = (ks * 4 + (lane >> 4)) ^ (brow & 7);
        bfv[nf] = *reinterpret_cast<const short8*>(&Bsm[brow * 64 + slot * 8]);
      }
#pragma unroll
      for (int mf = 0; mf < 2; ++mf)
#pragma unroll
        for (int nf = 0; nf < NFRAG; ++nf)
          acc[mf][nf] = __builtin_amdgcn_mfma_f32_16x16x32_bf16(af[mf], bfv[nf], acc[mf][nf], 0, 0, 0);
    }
    __syncthreads();
  }

#pragma unroll
  for (int mf = 0; mf < 2; ++mf) {
#pragma unroll
    for (int jj = 0; jj < 4; ++jj) {
      int Rg = blockIdx.x * 64 + wm * 32 + mf * 16 + (lane >> 4) * 4 + jj;
      int node = Rg / twol1;
      int lm = l * l + (Rg - node * twol1);
      size_t rowoff = (size_t)(node * L2DIM + lm);
#pragma unroll
      for (int nf = 0; nf < NFRAG; ++nf) {
        int colg = wn * WN_T + nf * 16 + (lane & 15);
        float vv = acc[mf][nf][jj];
        if (l == 0) vv += bias[colg];
        if (!SECOND) {
          outb[rowoff * ND + colg] = f2bf(vv);
        } else {
          outf[rowoff * ND + colg] = vv + resid[rowoff * ND + colg];
        }
      }
    }
  }
}

// ---------------------------------------------------------------------------
// Depthwise Gaunt tensor product (unchanged; compile-time coefficients).
// ---------------------------------------------------------------------------
__global__ __launch_bounds__(256, 2) void gaunt_kernel(
    const u16* __restrict__ hb, const float* __restrict__ wg,
    u16* __restrict__ tb) {
  int n = blockIdx.x, c = threadIdx.x;
  const u16* hr = hb + (size_t)n * (L2DIM * CHID) + c;
  float h[16];
#pragma unroll
  for (int i = 0; i < 16; ++i) h[i] = bf2f(hr[i * CHID]);

  float wgv[NPATHS];
  load_wgv(std::make_index_sequence<NPATHS>{}, wgv, wg, c);

  float t[16];
#pragma unroll
  for (int k = 0; k < 16; ++k) t[k] = 0.f;

  gaunt_terms(std::make_index_sequence<NNZ>{}, t, h, wgv);

  u16* tr = tb + (size_t)n * (L2DIM * CHID) + c;
#pragma unroll
  for (int k = 0; k < 16; ++k) tr[k * CHID] = f2bf(t[k]);
}

// ---------------------------------------------------------------------------
extern "C" void kernel_launch(void* const* d_in, const int* in_sizes, int n_in,
                              void* d_out, int out_size, void* d_ws, size_t ws_size,
                              hipStream_t stream) {
  const float* inputs = (const float*)d_in[0];
  // d_in[1] = batch (unused: drop paths disabled)
  const float* norm_w = (const float*)d_in[2];
  const float* norm_b = (const float*)d_in[3];
  const float* w1     = (const float*)d_in[4];
  const float* b1     = (const float*)d_in[5];
  const float* wga    = (const float*)d_in[6];
  const float* w2     = (const float*)d_in[7];
  const float* b2     = (const float*)d_in[8];
  float* out = (float*)d_out;

  uint8_t* ws = (uint8_t*)d_ws;
  u16*   w1t = (u16*)(ws + 16384);          // [4][256][384] bf16, 768 KB
  u16*   w2t = (u16*)(ws + 802816);         // [4][384][256] bf16, 768 KB
  u16*   xnb = (u16*)(ws + 1589248);        // [2048][16][384] bf16, 24 MB
  u16*   tb  = xnb;                         // reuse after GEMM1 consumed xnb
  u16*   hb  = (u16*)(ws + 26755072);       // [2048][16][256] bf16, 16 MB

  transpose_bf16_kernel<<<dim3(12, 12, 8), 256, 0, stream>>>(w1, w2, w1t, w2t);
  norm_kernel<<<NNODES, 256, 0, stream>>>(inputs, norm_w, norm_b, xnb);
  so3_gemm_kernel<CIN, CHID, false><<<dim3(224, 1, 4), 512, 0, stream>>>(
      xnb, w1t, b1, nullptr, hb, nullptr);
  gaunt_kernel<<<NNODES, 256, 0, stream>>>(hb, wga, tb);
  so3_gemm_kernel<CHID, CIN, true><<<dim3(224, 1, 4), 512, 0, stream>>>(
      tb, w2t, b2, inputs, nullptr, out);
}

// Round 6
// 86.817 us; speedup vs baseline: 4.9801x; 1.0613x over previous
//
#include <hip/hip_runtime.h>
#include <stdint.h>
#include <math.h>
#include <array>
#include <utility>

#ifndef M_PI
#define M_PI 3.14159265358979323846
#endif

#define NNODES 2048
#define L2DIM  16
#define CIN    384
#define CHID   256

typedef __attribute__((ext_vector_type(8))) short short8;
typedef __attribute__((ext_vector_type(4))) float f32x4;
typedef unsigned short u16;
typedef unsigned int   u32;

#define LOF(i) ((i) < 1 ? 0 : ((i) < 4 ? 1 : ((i) < 9 ? 2 : 3)))

static __device__ __forceinline__ u16 f2bf(float f) {
  u32 u = __builtin_bit_cast(u32, f);
  u = u + 0x7FFFu + ((u >> 16) & 1u);   // RNE
  return (u16)(u >> 16);
}
static __device__ __forceinline__ float bf2f(u16 b) {
  u32 u = ((u32)b) << 16;
  return __builtin_bit_cast(float, u);
}

// ===========================================================================
// COMPILE-TIME Gaunt coefficients (validated round 3: absmax 0.0625).
// ===========================================================================
constexpr double CPI = 3.14159265358979323846;

constexpr double csqrt(double x) {
  if (x <= 0.0) return 0.0;
  double y = x > 1.0 ? x : 1.0;
  for (int i = 0; i < 48; ++i) y = 0.5 * (y + x / y);
  return y;
}
constexpr double ccos(double x) {
  double r = x;
  while (r > CPI)  r -= 2.0 * CPI;
  while (r < -CPI) r += 2.0 * CPI;
  double r2 = r * r, term = 1.0, sum = 1.0;
  for (int i = 1; i <= 26; ++i) { term *= -r2 / ((2.0 * i - 1.0) * (2.0 * i)); sum += term; }
  return sum;
}
constexpr int iabs_c(int x) { return x < 0 ? -x : x; }

struct GLQ { double x[16]; double w[16]; };
constexpr GLQ build_gl() {
  GLQ g{};
  const int n = 16;
  for (int i = 0; i < n; ++i) {
    double x = ccos(CPI * (i + 0.75) / (n + 0.5));
    double p1 = 0.0, dp = 1.0;
    for (int it = 0; it < 40; ++it) {
      double p0 = 1.0; p1 = x;
      for (int k = 2; k <= n; ++k) { double p2 = ((2.0*k-1.0)*x*p1 - (k-1.0)*p0)/k; p0 = p1; p1 = p2; }
      dp = n * (x*p1 - p0) / (x*x - 1.0);
      x -= p1 / dp;
    }
    { double p0 = 1.0; p1 = x;
      for (int k = 2; k <= n; ++k) { double p2 = ((2.0*k-1.0)*x*p1 - (k-1.0)*p0)/k; p0 = p1; p1 = p2; }
      dp = n * (x*p1 - p0) / (x*x - 1.0); }
    g.x[i] = x;
    g.w[i] = 2.0 / ((1.0 - x*x) * dp * dp);
  }
  return g;
}
constexpr GLQ QG = build_gl();

struct PTab { double v[4][4][16]; };
constexpr PTab build_pbar() {
  PTab T{};
  for (int t = 0; t < 16; ++t) {
    double ct = QG.x[t];
    double st = csqrt(1.0 - ct * ct);
    double P[4][4] = {};
    P[0][0] = csqrt(1.0 / (4.0 * CPI));
    for (int m = 1; m <= 3; ++m)
      P[m][m] = csqrt((2.0*m + 1.0) / (2.0*m)) * st * P[m-1][m-1];
    for (int m = 0; m <= 3; ++m) {
      if (m + 1 <= 3) P[m+1][m] = csqrt(2.0*m + 3.0) * ct * P[m][m];
      for (int l = m + 2; l <= 3; ++l) {
        double aa = csqrt((4.0*(double)l*l - 1.0) / ((double)l*l - (double)m*m));
        double bb = csqrt(((double)(l-1)*(l-1) - (double)m*m) / (4.0*(double)(l-1)*(l-1) - 1.0));
        P[l][m] = aa * (ct * P[l-1][m] - bb * P[l-2][m]);
      }
    }
    for (int l = 0; l < 4; ++l)
      for (int m = 0; m <= l; ++m) T.v[l][m][t] = P[l][m];
  }
  return T;
}
constexpr PTab PT = build_pbar();

constexpr double phi_int(int m1, int m2, int m3) {
  const double SQ2 = 1.41421356237309504880;
  int neg = (m1 < 0) + (m2 < 0) + (m3 < 0);
  if (neg & 1) return 0.0;
  int a = iabs_c(m1), b = iabs_c(m2), c = iabs_c(m3);
  int nz = (a > 0) + (b > 0) + (c > 0);
  if (nz == 0) return 2.0 * CPI;
  if (nz == 1) return 0.0;
  if (nz == 2) {
    int p = 0, q = 0;
    if (a == 0) { p = b; q = c; } else if (b == 0) { p = a; q = c; } else { p = a; q = b; }
    return (p == q) ? 2.0 * CPI : 0.0;
  }
  if (neg == 0) {
    double v = 0.0;
    if (iabs_c(a - b) == c && a != b) v += 1.0;
    if (a + b == c) v += 1.0;
    return SQ2 * CPI * v;
  }
  int p = 0, q = 0, r = 0;
  if (m1 > 0)      { p = a; q = b; r = c; }
  else if (m2 > 0) { p = b; q = a; r = c; }
  else             { p = c; q = a; r = b; }
  double v = 0.0;
  if (q != r && p == iabs_c(q - r)) v += 1.0;
  if (p == q + r) v -= 1.0;
  return SQ2 * CPI * v;
}

constexpr bool path_ok(int l1, int l2, int l3) {
  int lo = l1 > l2 ? l1 - l2 : l2 - l1;
  return l3 >= lo && l3 <= l1 + l2 && (((l1 + l2 + l3) & 1) == 0);
}
constexpr bool term_ok(int m1, int m2, int m3) {
  int aa = iabs_c(m1), bb = iabs_c(m2), cc = iabs_c(m3);
  int neg = (m1 < 0) + (m2 < 0) + (m3 < 0);
  if (neg & 1) return false;
  return (aa + bb == cc) || (bb + cc == aa) || (cc + aa == bb);
}
constexpr int count_paths() {
  int n = 0;
  for (int l1 = 0; l1 < 4; ++l1) for (int l2 = 0; l2 < 4; ++l2) for (int l3 = 0; l3 < 4; ++l3)
    if (path_ok(l1, l2, l3)) ++n;
  return n;
}
constexpr int NPATHS = count_paths();   // 23
constexpr int NTMAX  = 512;

constexpr double term_g(int l1, int m1, int l2, int m2, int l3, int m3) {
  double ph = phi_int(m1, m2, m3);
  if (ph == 0.0) return 0.0;
  int a = iabs_c(m1), b = iabs_c(m2), c = iabs_c(m3);
  double s = 0.0;
  for (int t = 0; t < 16; ++t)
    s += QG.w[t] * PT.v[l1][a][t] * PT.v[l2][b][t] * PT.v[l3][c][t];
  double g = ph * s;
  double fan = (l3 == 0) ? 4.0 : (l3 == 1 ? 6.0 : (l3 == 2 ? 7.0 : 6.0));
  return g * csqrt((2.0 * (double)l3 + 1.0) / fan);
}

struct TermG { float g; unsigned char i, j, k, p; };
struct PathT { unsigned char l1, l2, l3; };
struct TGAll { TermG t[NTMAX]; int n; };
constexpr TGAll build_all() {
  TGAll r{};
  r.n = 0;
  int p = 0;
  for (int l1 = 0; l1 < 4; ++l1) for (int l2 = 0; l2 < 4; ++l2) for (int l3 = 0; l3 < 4; ++l3) {
    if (!path_ok(l1, l2, l3)) continue;
    for (int m1 = -l1; m1 <= l1; ++m1) for (int m2 = -l2; m2 <= l2; ++m2) for (int m3 = -l3; m3 <= l3; ++m3) {
      if (!term_ok(m1, m2, m3)) continue;
      double g = term_g(l1, m1, l2, m2, l3, m3);
      if (g > 1e-10 || g < -1e-10) {
        r.t[r.n].g = (float)g;
        r.t[r.n].i = (unsigned char)(l1 * l1 + l1 + m1);
        r.t[r.n].j = (unsigned char)(l2 * l2 + l2 + m2);
        r.t[r.n].k = (unsigned char)(l3 * l3 + l3 + m3);
        r.t[r.n].p = (unsigned char)p;
        ++r.n;
      }
    }
    ++p;
  }
  return r;
}
constexpr TGAll TGA = build_all();
constexpr int NNZ = TGA.n;

constexpr std::array<PathT, NPATHS> build_paths() {
  std::array<PathT, NPATHS> a{};
  int n = 0;
  for (int l1 = 0; l1 < 4; ++l1) for (int l2 = 0; l2 < 4; ++l2) for (int l3 = 0; l3 < 4; ++l3)
    if (path_ok(l1, l2, l3)) a[n++] = PathT{(unsigned char)l1, (unsigned char)l2, (unsigned char)l3};
  return a;
}
constexpr auto PATHS_ARR = build_paths();

template <size_t... Is>
__device__ __forceinline__ void gaunt_terms(std::index_sequence<Is...>,
    float* __restrict__ t, const float* __restrict__ h,
    const float* __restrict__ wgv) {
  ((t[TGA.t[Is].k] = fmaf(TGA.t[Is].g * wgv[TGA.t[Is].p],
                          h[TGA.t[Is].i] * h[TGA.t[Is].j],
                          t[TGA.t[Is].k])), ...);
}
template <size_t... Ps>
__device__ __forceinline__ void load_wgv(std::index_sequence<Ps...>,
    float* __restrict__ wgv, const float* __restrict__ wg, int c) {
  ((wgv[Ps] = wg[(size_t)(((int)PATHS_ARR[Ps].l1 * 4 + (int)PATHS_ARR[Ps].l2) * 4
                          + (int)PATHS_ARR[Ps].l3) * CHID + c]), ...);
}

// ---------------------------------------------------------------------------
// prep_kernel: blocks [0, 2048) do the equivariant layernorm (one node each);
// blocks [2048, 3200) do the weight transpose+bf16 (w1: 4 mats 384x256,
// w2: 4 mats 256x384). Independent work merged to save a launch.
// ---------------------------------------------------------------------------
__global__ __launch_bounds__(256) void prep_kernel(
    const float* __restrict__ x, const float* __restrict__ nw,
    const float* __restrict__ nb, u16* __restrict__ xnb,
    const float* __restrict__ w1, const float* __restrict__ w2,
    u16* __restrict__ w1t, u16* __restrict__ w2t) {
  int bid = blockIdx.x, tid = threadIdx.x;
  if (bid >= NNODES) {
    // ---- transpose path ----
    __shared__ float tile[32][33];
    int b2 = bid - NNODES;
    int z = b2 / 144, rem = b2 % 144;
    int by = rem / 12, bx = rem % 12;
    int R = z < 4 ? 384 : 256, C = z < 4 ? 256 : 384;
    int r0 = by * 32, c0 = bx * 32;
    if (r0 >= R || c0 >= C) return;
    const float* s = (z < 4 ? w1 : w2) + (size_t)(z & 3) * R * C;
    u16* d = (z < 4 ? w1t : w2t) + (size_t)(z & 3) * R * C;
    int tx = tid & 31, ty = tid >> 5;
    for (int rr = ty; rr < 32; rr += 8)
      tile[rr][tx] = s[(size_t)(r0 + rr) * C + (c0 + tx)];
    __syncthreads();
    for (int cc = ty; cc < 32; cc += 8)
      d[(size_t)(c0 + cc) * R + (r0 + tx)] = f2bf(tile[tx][cc]);
    return;
  }
  // ---- norm path ----
  int n = bid;
  const float* xr = x + (size_t)n * (L2DIM * CIN);
  __shared__ float2 red[4];
  float4 v[6];
  float ssq = 0.f, m0p = 0.f;
#pragma unroll
  for (int q = 0; q < 6; ++q) {
    v[q] = reinterpret_cast<const float4*>(xr)[tid * 6 + q];
    ssq += v[q].x*v[q].x + v[q].y*v[q].y + v[q].z*v[q].z + v[q].w*v[q].w;
  }
  if (tid < 16) {   // these 16 threads hold exactly row 0 (16*24 = 384)
#pragma unroll
    for (int q = 0; q < 6; ++q) m0p += v[q].x + v[q].y + v[q].z + v[q].w;
  }
  float a = m0p, b = ssq;
#pragma unroll
  for (int off = 32; off > 0; off >>= 1) { a += __shfl_down(a, off, 64); b += __shfl_down(b, off, 64); }
  int lane = tid & 63, wid = tid >> 6;
  if (lane == 0) red[wid] = make_float2(a, b);
  __syncthreads();
  float sum0 = red[0].x + red[1].x + red[2].x + red[3].x;
  float ssqt = red[0].y + red[1].y + red[2].y + red[3].y;
  float mean0 = sum0 * (1.0f / CIN);
  float ss = ssqt - (float)CIN * mean0 * mean0;
  float rstd = rsqrtf(ss * (1.0f / (L2DIM * CIN)) + 1e-5f);

  int lm = tid >> 4;
  int l = LOF(lm);
  bool row0 = (lm == 0);
  int cbase = (tid & 15) * 24;
  u16* orow = xnb + (size_t)n * (L2DIM * CIN) + (size_t)tid * 24;
#pragma unroll
  for (int q = 0; q < 6; ++q) {
    int c = cbase + q * 4;
    float4 w4 = *reinterpret_cast<const float4*>(&nw[l * CIN + c]);
    float4 b4 = row0 ? *reinterpret_cast<const float4*>(&nb[c]) : make_float4(0,0,0,0);
    float sub = row0 ? mean0 : 0.f;
    float o0 = (v[q].x - sub) * rstd * w4.x + b4.x;
    float o1 = (v[q].y - sub) * rstd * w4.y + b4.y;
    float o2 = (v[q].z - sub) * rstd * w4.z + b4.z;
    float o3 = (v[q].w - sub) * rstd * w4.w + b4.w;
    ushort4 pk;
    pk.x = f2bf(o0); pk.y = f2bf(o1); pk.z = f2bf(o2); pk.w = f2bf(o3);
    *reinterpret_cast<ushort4*>(&orow[q * 4]) = pk;
  }
}

// ---------------------------------------------------------------------------
// Per-degree GEMM, 2-phase pipelined (T3-minimum): double-buffered LDS,
// stage(kt+1) issued BEFORE compute(kt), ONE __syncthreads per K-tile
// (its vmcnt(0) drain lands after compute has covered the load latency).
// BM=64, BN=256 (gemm1) / 192 (gemm2 halves), BK=64, 512 thr = 8 waves.
// ---------------------------------------------------------------------------
template <int KD, int ND, int BN, bool SECOND>
__global__ __launch_bounds__(512) void so3_gemm_kernel(
    const u16* __restrict__ A, const u16* __restrict__ BT,
    const float* __restrict__ bias, const float* __restrict__ resid,
    u16* __restrict__ outb, float* __restrict__ outf) {
  constexpr int NFRAG = BN / 64;            // frags/wave in N (4 or 3)
  constexpr int WN_T = BN / 4;              // wave tile N (64 or 48)
  constexpr int KT = KD / 64;               // K-tiles (6 or 4)
  static_assert((BN % 64) == 0 && NFRAG * 16 == WN_T, "");
  int l = blockIdx.z;
  int twol1 = 2 * l + 1;
  int mtiles = (NNODES * twol1) >> 6;
  if ((int)blockIdx.x >= mtiles) return;
  int col0 = blockIdx.y * BN;
  int tid = threadIdx.x, lane = tid & 63, wid = tid >> 6;
  int wm = wid >> 2, wn = wid & 3;

  __shared__ u16 Asm[2][64 * 64];           // 2 x  8 KB
  __shared__ u16 Bsm[2][BN * 64];           // 2 x 32/24 KB

  // A staging source: one global_load_lds covers 64x64 (512 thr x 16 B).
  int ar = tid >> 3;
  const u16* asrc;
  {
    int Rg = blockIdx.x * 64 + ar;
    int node = Rg / twol1;
    int lm = l * l + (Rg - node * twol1);
    asrc = A + (size_t)(node * L2DIM + lm) * KD + ((tid & 7) ^ (ar & 7)) * 8;
  }
  const u16* bsrc[BN / 64];
#pragma unroll
  for (int i = 0; i < BN / 64; ++i) {
    int r = i * 64 + (tid >> 3);
    bsrc[i] = BT + (size_t)(l * ND + col0 + r) * KD + ((tid & 7) ^ (r & 7)) * 8;
  }

  auto stage = [&](int buf, int kt) {
    __builtin_amdgcn_global_load_lds(
        (const __attribute__((address_space(1))) void*)(asrc + kt * 64),
        (__attribute__((address_space(3))) void*)(&Asm[buf][wid * 512]),
        16, 0, 0);
#pragma unroll
    for (int i = 0; i < BN / 64; ++i)
      __builtin_amdgcn_global_load_lds(
          (const __attribute__((address_space(1))) void*)(bsrc[i] + kt * 64),
          (__attribute__((address_space(3))) void*)(&Bsm[buf][i * 4096 + wid * 512]),
          16, 0, 0);
  };

  f32x4 acc[2][NFRAG];
#pragma unroll
  for (int i = 0; i < 2; ++i)
#pragma unroll
    for (int j = 0; j < NFRAG; ++j) acc[i][j] = (f32x4){0.f, 0.f, 0.f, 0.f};

  stage(0, 0);
  __syncthreads();
#pragma unroll
  for (int kt = 0; kt < KT; ++kt) {
    int cur = kt & 1;
    if (kt + 1 < KT) stage(cur ^ 1, kt + 1);
#pragma unroll
    for (int ks = 0; ks < 2; ++ks) {
      short8 af[2], bfv[NFRAG];
#pragma unroll
      for (int mf = 0; mf < 2; ++mf) {
        int row = wm * 32 + mf * 16 + (lane & 15);
        int slot = (ks * 4 + (lane >> 4)) ^ (row & 7);
        af[mf] = *reinterpret_cast<const short8*>(&Asm[cur][row * 64 + slot * 8]);
      }
#pragma unroll
      for (int nf = 0; nf < NFRAG; ++nf) {
        int brow = wn * WN_T + nf * 16 + (lane & 15);
        int slot = (ks * 4 + (lane >> 4)) ^ (brow & 7);
        bfv[nf] = *reinterpret_cast<const short8*>(&Bsm[cur][brow * 64 + slot * 8]);
      }
#pragma unroll
      for (int mf = 0; mf < 2; ++mf)
#pragma unroll
        for (int nf = 0; nf < NFRAG; ++nf)
          acc[mf][nf] = __builtin_amdgcn_mfma_f32_16x16x32_bf16(af[mf], bfv[nf], acc[mf][nf], 0, 0, 0);
    }
    __syncthreads();   // drains stage(kt+1) loads; protects buf reuse
  }

#pragma unroll
  for (int mf = 0; mf < 2; ++mf) {
#pragma unroll
    for (int jj = 0; jj < 4; ++jj) {
      int Rg = blockIdx.x * 64 + wm * 32 + mf * 16 + (lane >> 4) * 4 + jj;
      int node = Rg / twol1;
      int lm = l * l + (Rg - node * twol1);
      size_t rowoff = (size_t)(node * L2DIM + lm);
#pragma unroll
      for (int nf = 0; nf < NFRAG; ++nf) {
        int colg = col0 + wn * WN_T + nf * 16 + (lane & 15);
        float vv = acc[mf][nf][jj];
        if (l == 0) vv += bias[colg];
        if (!SECOND) {
          outb[rowoff * ND + colg] = f2bf(vv);
        } else {
          outf[rowoff * ND + colg] = vv + resid[rowoff * ND + colg];
        }
      }
    }
  }
}

// ---------------------------------------------------------------------------
// Depthwise Gaunt tensor product (compile-time coefficients).
// ---------------------------------------------------------------------------
__global__ __launch_bounds__(256, 2) void gaunt_kernel(
    const u16* __restrict__ hb, const float* __restrict__ wg,
    u16* __restrict__ tb) {
  int n = blockIdx.x, c = threadIdx.x;
  const u16* hr = hb + (size_t)n * (L2DIM * CHID) + c;
  float h[16];
#pragma unroll
  for (int i = 0; i < 16; ++i) h[i] = bf2f(hr[i * CHID]);

  float wgv[NPATHS];
  load_wgv(std::make_index_sequence<NPATHS>{}, wgv, wg, c);

  float t[16];
#pragma unroll
  for (int k = 0; k < 16; ++k) t[k] = 0.f;

  gaunt_terms(std::make_index_sequence<NNZ>{}, t, h, wgv);

  u16* tr = tb + (size_t)n * (L2DIM * CHID) + c;
#pragma unroll
  for (int k = 0; k < 16; ++k) tr[k * CHID] = f2bf(t[k]);
}

// ---------------------------------------------------------------------------
extern "C" void kernel_launch(void* const* d_in, const int* in_sizes, int n_in,
                              void* d_out, int out_size, void* d_ws, size_t ws_size,
                              hipStream_t stream) {
  const float* inputs = (const float*)d_in[0];
  // d_in[1] = batch (unused: drop paths disabled)
  const float* norm_w = (const float*)d_in[2];
  const float* norm_b = (const float*)d_in[3];
  const float* w1     = (const float*)d_in[4];
  const float* b1     = (const float*)d_in[5];
  const float* wga    = (const float*)d_in[6];
  const float* w2     = (const float*)d_in[7];
  const float* b2     = (const float*)d_in[8];
  float* out = (float*)d_out;

  uint8_t* ws = (uint8_t*)d_ws;
  u16*   w1t = (u16*)(ws + 16384);          // [4][256][384] bf16, 768 KB
  u16*   w2t = (u16*)(ws + 802816);         // [4][384][256] bf16, 768 KB
  u16*   xnb = (u16*)(ws + 1589248);        // [2048][16][384] bf16, 24 MB
  u16*   tb  = xnb;                         // reuse after GEMM1 consumed xnb
  u16*   hb  = (u16*)(ws + 26755072);       // [2048][16][256] bf16, 16 MB

  prep_kernel<<<NNODES + 1152, 256, 0, stream>>>(
      inputs, norm_w, norm_b, xnb, w1, w2, w1t, w2t);
  so3_gemm_kernel<CIN, CHID, 256, false><<<dim3(224, 1, 4), 512, 0, stream>>>(
      xnb, w1t, b1, nullptr, hb, nullptr);
  gaunt_kernel<<<NNODES, 256, 0, stream>>>(hb, wga, tb);
  so3_gemm_kernel<CHID, CIN, 192, true><<<dim3(224, 2, 4), 512, 0, stream>>>(
      tb, w2t, b2, inputs, nullptr, out);
}